// Round 11
// baseline (4203.896 us; speedup 1.0000x reference)
//
#include <hip/hip_runtime.h>
#include <math.h>

#define BATCH 512
#define TM1   31
#define DIMD  256

typedef _Float16 f16;
typedef _Float16 half2v __attribute__((ext_vector_type(2)));
typedef _Float16 half8 __attribute__((ext_vector_type(8)));
typedef float floatx16 __attribute__((ext_vector_type(16)));
typedef unsigned long long u64;

__device__ __forceinline__ float sigmf(float x) { return 1.f / (1.f + __expf(-x)); }

__device__ __forceinline__ float tanh_fast(float x) {
    float ax = fabsf(x);
    float t  = __expf(-2.f * ax);
    float r  = (1.f - t) / (1.f + t);
    return copysignf(r, x);
}

__device__ __forceinline__ void split16(float x, f16* hi, f16* lo) {
    f16 h = (f16)x;
    *hi = h;
    *lo = (f16)(x - (float)h);
}

// Agent-scope (L3-coherent) 8B accesses: cross-XCD safe without cache invalidates.
__device__ __forceinline__ void st_agent(u64* p, u64 v) {
    __hip_atomic_store(p, v, __ATOMIC_RELAXED, __HIP_MEMORY_SCOPE_AGENT);
}
__device__ __forceinline__ u64 ld_agent(const u64* p) {
    return __hip_atomic_load(p, __ATOMIC_RELAXED, __HIP_MEMORY_SCOPE_AGENT);
}

__device__ __forceinline__ float blockReduceSum256(float v, float* sred) {
#pragma unroll
    for (int m = 32; m > 0; m >>= 1) v += __shfl_xor(v, m);
    __syncthreads();
    if ((threadIdx.x & 63) == 0) sred[threadIdx.x >> 6] = v;
    __syncthreads();
    return sred[0] + sred[1] + sred[2] + sred[3];
}

__device__ __forceinline__ float blockReduceMax256(float v, float* sred) {
#pragma unroll
    for (int m = 32; m > 0; m >>= 1) v = fmaxf(v, __shfl_xor(v, m));
    __syncthreads();
    if ((threadIdx.x & 63) == 0) sred[threadIdx.x >> 6] = v;
    __syncthreads();
    return fmaxf(fmaxf(sred[0], sred[1]), fmaxf(sred[2], sred[3]));
}

// ---------------------------------------------------------------------------
// prep + t2s fused; also zeroes the producer->consumer counters.
// ---------------------------------------------------------------------------
__global__ __launch_bounds__(256) void prep_t2s_kernel(
    const float* __restrict__ inputs,
    const float* __restrict__ eWih, const float* __restrict__ eWhh,
    const float* __restrict__ ebih, const float* __restrict__ ebhh,
    const float* __restrict__ dW1,  const float* __restrict__ dWhh,
    const float* __restrict__ dbih, const float* __restrict__ dbhh,
    const float* __restrict__ Wd,   const float* __restrict__ bd,
    f16* __restrict__ eWhi, f16* __restrict__ eWlo,
    f16* __restrict__ dWchi, f16* __restrict__ dWclo,
    f16* __restrict__ Vwhi, f16* __restrict__ Vwlo,
    float* __restrict__ ebcomb, float* __restrict__ dbias,
    f16* __restrict__ t2s, unsigned* __restrict__ cnt)
{
    __shared__ float sX[TM1 * DIMD];
    __shared__ float sWd[TM1 * TM1];
    int b = blockIdx.x, tid = threadIdx.x;
    int idx = b * 256 + tid;
    const int stride = 512 * 256;

    for (int i = tid; i < TM1 * DIMD; i += 256) {
        int tt = i >> 8, d = i & 255;
        sX[i] = inputs[((size_t)b * TM1 + tt) * 257 + 1 + d];
    }
    for (int i = tid; i < TM1 * TM1; i += 256) sWd[i] = Wd[i];
    __syncthreads();
    int d = tid;
    for (int s = 0; s < TM1; s++) {
        float acc = bd[s];
        for (int tt = 0; tt < TM1; tt++) acc += sX[tt * DIMD + d] * sWd[s * TM1 + tt];
        t2s[((size_t)b * TM1 + s) * DIMD + d] = (f16)acc;
    }

    for (int g = idx; g < 2048 * 96; g += stride) {
        int n = g / 96, k0 = (g % 96) * 8;
        const float* src = (k0 < 256) ? (eWih + n * 256 + k0)
                                      : (eWhh + n * 512 + (k0 - 256));
        float4 v0 = *(const float4*)src;
        float4 v1 = *(const float4*)(src + 4);
        float vv[8] = {v0.x, v0.y, v0.z, v0.w, v1.x, v1.y, v1.z, v1.w};
        f16 hi[8], lo[8];
#pragma unroll
        for (int e = 0; e < 8; e++) split16(vv[e], &hi[e], &lo[e]);
        *(half8*)(eWhi + n * 768 + k0) = *(half8*)hi;
        *(half8*)(eWlo + n * 768 + k0) = *(half8*)lo;
    }
    for (int g = idx; g < 2560 * 128; g += stride) {
        int n = g >> 7, k0 = (g & 127) * 8;
        float vv[8] = {};
        if (n < 512) {
            const float* src = dW1 + n * 1536 + k0;
            float4 v0 = *(const float4*)src, v1 = *(const float4*)(src + 4);
            vv[0]=v0.x; vv[1]=v0.y; vv[2]=v0.z; vv[3]=v0.w;
            vv[4]=v1.x; vv[5]=v1.y; vv[6]=v1.z; vv[7]=v1.w;
        } else if (k0 < 512) {
            const float* src = dWhh + (n - 512) * 512 + k0;
            float4 v0 = *(const float4*)src, v1 = *(const float4*)(src + 4);
            vv[0]=v0.x; vv[1]=v0.y; vv[2]=v0.z; vv[3]=v0.w;
            vv[4]=v1.x; vv[5]=v1.y; vv[6]=v1.z; vv[7]=v1.w;
        }
        f16 hi[8], lo[8];
#pragma unroll
        for (int e = 0; e < 8; e++) split16(vv[e], &hi[e], &lo[e]);
        *(half8*)(dWchi + n * 1024 + k0) = *(half8*)hi;
        *(half8*)(dWclo + n * 1024 + k0) = *(half8*)lo;
    }
    for (int g = idx; g < 512 * 64; g += stride) {
        int n = g >> 6, k0 = (g & 63) * 8;
        const float* src = dW1 + n * 1536 + 1024 + k0;
        float4 v0 = *(const float4*)src, v1 = *(const float4*)(src + 4);
        float vv[8] = {v0.x, v0.y, v0.z, v0.w, v1.x, v1.y, v1.z, v1.w};
        f16 hi[8], lo[8];
#pragma unroll
        for (int e = 0; e < 8; e++) split16(vv[e], &hi[e], &lo[e]);
        *(half8*)(Vwhi + n * 512 + k0) = *(half8*)hi;
        *(half8*)(Vwlo + n * 512 + k0) = *(half8*)lo;
    }
    for (int i = idx; i < 2048; i += stride) ebcomb[i] = ebih[i] + ebhh[i];
    for (int i = idx; i < 2560; i += stride)
        dbias[i] = (i < 512) ? 0.f : (dbih[i - 512] + dbhh[i - 512]);
    for (int i = idx; i < 512; i += stride) cnt[i] = 0u;
}

// ---------------------------------------------------------------------------
// 64x64 gemm tile, fp16x2, A loaded via agent-scope atomic u64 (L3-coherent,
// bypasses stale per-XCD L2); W hi/lo via normal cached loads. XOR-swizzled
// LDS + register prefetch (R9-validated pipeline shape).
// ---------------------------------------------------------------------------
__device__ __forceinline__ void gemm_tile_aA(
    const f16* __restrict__ A, int lda,
    const f16* __restrict__ Whi, const f16* __restrict__ Wlo, int ldw,
    const float* __restrict__ bias, bool addBias,
    f16* __restrict__ C, int ldc,
    int kbeg, int kend, int m0, int n0, char* smem)
{
    f16* sAh = (f16*)smem;
    f16* sWh = (f16*)(smem + 8192);
    f16* sWl = (f16*)(smem + 16384);
    int tid = threadIdx.x;
    int lane = tid & 63, wid = tid >> 6;
    int wm = wid >> 1, wn = wid & 1;
    int rl = lane & 31, kq = lane >> 5;
    int sr = tid >> 2;
    int g0 = (tid & 3) * 2;
    int s0 = sr * 64 + ((g0 ^ (sr & 7)) * 8);
    int s1 = sr * 64 + (((g0 + 1) ^ (sr & 7)) * 8);
    int arow = (wm * 32 + rl) * 64;
    int wrow = (wn * 32 + rl) * 64;
    int sw = (rl & 7);

    const f16* pA  = A   + (size_t)(m0 + sr) * lda + g0 * 8;
    const f16* pWh = Whi + (size_t)(n0 + sr) * ldw + g0 * 8;
    const f16* pWl = Wlo + (size_t)(n0 + sr) * ldw + g0 * 8;

    u64 rA0 = ld_agent((const u64*)(pA + kbeg));
    u64 rA1 = ld_agent((const u64*)(pA + kbeg + 4));
    u64 rA2 = ld_agent((const u64*)(pA + kbeg + 8));
    u64 rA3 = ld_agent((const u64*)(pA + kbeg + 12));
    float4 rWh0 = *(const float4*)(pWh + kbeg);
    float4 rWh1 = *(const float4*)(pWh + kbeg + 8);
    float4 rWl0 = *(const float4*)(pWl + kbeg);
    float4 rWl1 = *(const float4*)(pWl + kbeg + 8);

    floatx16 acc = {};
    for (int k0 = kbeg; k0 < kend; k0 += 64) {
        __syncthreads();
        *(u64*)&sAh[s0] = rA0; *(u64*)&sAh[s0 + 4] = rA1;
        *(u64*)&sAh[s1] = rA2; *(u64*)&sAh[s1 + 4] = rA3;
        *(float4*)&sWh[s0] = rWh0; *(float4*)&sWh[s1] = rWh1;
        *(float4*)&sWl[s0] = rWl0; *(float4*)&sWl[s1] = rWl1;
        __syncthreads();
        int kn = k0 + 64;
        if (kn < kend) {
            rA0 = ld_agent((const u64*)(pA + kn));
            rA1 = ld_agent((const u64*)(pA + kn + 4));
            rA2 = ld_agent((const u64*)(pA + kn + 8));
            rA3 = ld_agent((const u64*)(pA + kn + 12));
            rWh0 = *(const float4*)(pWh + kn); rWh1 = *(const float4*)(pWh + kn + 8);
            rWl0 = *(const float4*)(pWl + kn); rWl1 = *(const float4*)(pWl + kn + 8);
        }
#pragma unroll
        for (int kk = 0; kk < 64; kk += 16) {
            int lg = (kk >> 3) + kq;
            int off = ((lg ^ sw) * 8);
            half8 ah = *(const half8*)&sAh[arow + off];
            half8 wh = *(const half8*)&sWh[wrow + off];
            half8 wl = *(const half8*)&sWl[wrow + off];
            acc = __builtin_amdgcn_mfma_f32_32x32x16_f16(ah, wh, acc, 0, 0, 0);
            acc = __builtin_amdgcn_mfma_f32_32x32x16_f16(ah, wl, acc, 0, 0, 0);
        }
    }
    int col = n0 + wn * 32 + rl;
    float bv = addBias ? bias[col] : 0.f;
#pragma unroll
    for (int rr = 0; rr < 16; ++rr) {
        int row = m0 + wm * 32 + (rr & 3) + 8 * (rr >> 2) + 4 * kq;
        C[(size_t)row * ldc + col] = (f16)(acc[rr] + bv);
    }
}

// ---------------------------------------------------------------------------
// FUSED encoder step: blocks 0..511 = producer (LSTM finalize t-1 + attention
// t, batch b = bid; writes A row via agent atomics, signals cntE[t][b>>6]).
// Blocks 512..1023 = consumer gemm (NT=32 x MT=8 x KS=2) computing g(t).
// Capacity proof: launch_bounds(256,4) + 24KB LDS -> >=4 blocks/CU -> all
// 1024 blocks co-resident -> spin-wait is deadlock-free.
// ---------------------------------------------------------------------------
__global__ __launch_bounds__(256, 4) void enc_fused(
    const float* __restrict__ inputs, const f16* __restrict__ t2s,
    const float* __restrict__ Wc, const float* __restrict__ bc,
    const float* __restrict__ Wa, const float* __restrict__ ba,
    f16* __restrict__ g, long long gstride,
    float* __restrict__ hc,
    f16* __restrict__ Ahi, f16* __restrict__ enchi,
    float* __restrict__ hc_dec,
    const f16* __restrict__ eWhi, const f16* __restrict__ eWlo,
    const float* __restrict__ ebcomb,
    unsigned* __restrict__ cntE, int t)
{
    __shared__ __align__(16) char smem[24576];
    int bid = blockIdx.x, tid = threadIdx.x;

    if (bid >= 512) {
        // ---------------- consumer: gemm A(t) @ eW^T -> g(t) ----------------
        if (t >= TM1) return;
        int c = bid - 512;
        int nbase = c & 31, mt = (c >> 5) & 7, ks = c >> 8;
        if (tid == 0) {
            while (__hip_atomic_load(&cntE[t * 8 + mt], __ATOMIC_RELAXED,
                                     __HIP_MEMORY_SCOPE_AGENT) < 64u)
                __builtin_amdgcn_s_sleep(2);
        }
        __syncthreads();
        gemm_tile_aA(Ahi, 768, eWhi, eWlo, 768, ebcomb, ks == 0,
                     g + (size_t)ks * gstride, 2048,
                     ks * 384, ks * 384 + 384, mt * 64, nbase * 64, smem);
        return;
    }

    // ---------------- producer: batch b ----------------
    float* sh_hc = (float*)smem;              // 1024 f
    f16*   sA    = (f16*)(smem + 4096);       // 768 h
    float* t1s   = (float*)(smem + 5632);     // 32 f
    float* sred  = (float*)(smem + 5760);     // 4 f
    int b = bid;

    if (t > 0) {
        int e = tid * 2;
        const f16* gp = g + (size_t)b * 2048 + e;
        float gi0 = 0.f, gi1 = 0.f, gf0 = 0.f, gf1 = 0.f;
        float gg0 = 0.f, gg1 = 0.f, go0 = 0.f, go1 = 0.f;
#pragma unroll
        for (int s = 0; s < 2; s++) {
            const f16* q = gp + s * gstride;
            half2v a = *(const half2v*)(q);
            half2v f = *(const half2v*)(q + 512);
            half2v gv = *(const half2v*)(q + 1024);
            half2v o = *(const half2v*)(q + 1536);
            gi0 += (float)a[0]; gi1 += (float)a[1];
            gf0 += (float)f[0]; gf1 += (float)f[1];
            gg0 += (float)gv[0]; gg1 += (float)gv[1];
            go0 += (float)o[0]; go1 += (float)o[1];
        }
        float2 cpv = *(const float2*)(hc + b * 1024 + 512 + e);
        float c20 = sigmf(gf0) * cpv.x + sigmf(gi0) * tanh_fast(gg0);
        float c21 = sigmf(gf1) * cpv.y + sigmf(gi1) * tanh_fast(gg1);
        float h20 = sigmf(go0) * tanh_fast(c20);
        float h21 = sigmf(go1) * tanh_fast(c21);
        *(float2*)(hc + b * 1024 + e) = make_float2(h20, h21);
        *(float2*)(hc + b * 1024 + 512 + e) = make_float2(c20, c21);
        sh_hc[e] = h20; sh_hc[e + 1] = h21;
        sh_hc[512 + e] = c20; sh_hc[512 + e + 1] = c21;
        half2v hv; hv[0] = (f16)h20; hv[1] = (f16)h21;
        *(half2v*)(enchi + ((size_t)b * TM1 + (t - 1)) * 512 + e) = hv;
    } else {
        for (int j = tid; j < 1024; j += 256) { sh_hc[j] = 0.f; hc[b * 1024 + j] = 0.f; }
    }
    if (t == TM1) {
        for (int j = tid; j < 1024; j += 256) hc_dec[b * 1024 + j] = 0.f;
        return;
    }
    __syncthreads();

    if (tid < 248) {
        int s = tid >> 3, l8 = tid & 7;
        const float* wrow = Wc + s * 1024;
        float p = 0.f;
        for (int j = l8 * 4; j < 1024; j += 32) {
            float4 w4 = *(const float4*)(wrow + j);
            float4 h4 = *(const float4*)(&sh_hc[j]);
            p += w4.x * h4.x + w4.y * h4.y + w4.z * h4.z + w4.w * h4.w;
        }
        p += __shfl_xor(p, 1); p += __shfl_xor(p, 2); p += __shfl_xor(p, 4);
        if (l8 == 0) t1s[s] = p + bc[s];
    }
    __syncthreads();

    int d = tid;
    float sc = ba[0];
    const f16* t2p = t2s + ((size_t)b * TM1) * DIMD + d;
    for (int s = 0; s < TM1; s++) sc += tanh_fast(t1s[s] + (float)t2p[s * DIMD]) * Wa[s];
    float mx = blockReduceMax256(sc, sred);
    float ex = __expf(sc - mx);
    float sm = blockReduceSum256(ex, sred);
    float w = (ex / sm) * inputs[((size_t)b * TM1 + t) * 257 + 1 + d];
    sA[tid] = (f16)w;
    for (int j = tid; j < 512; j += 256) sA[256 + j] = (f16)sh_hc[j];
    __syncthreads();
    if (tid < 192)
        st_agent((u64*)(Ahi + (size_t)b * 768) + tid, *(const u64*)&sA[tid * 4]);
    __syncthreads();   // barrier waitcnt drains all waves' atomic stores
    if (tid == 0)
        __hip_atomic_fetch_add(&cntE[t * 8 + (b >> 6)], 1u,
                               __ATOMIC_RELEASE, __HIP_MEMORY_SCOPE_AGENT);
}

// ---------------------------------------------------------------------------
// FUSED decoder step: blocks 0..511 = producer (attention + ctx + y_tilde +
// LSTM for batch b; writes hd row via agent atomics, signals cntD[t][b>>6]).
// Blocks 512..1023 = consumer gemm computing gu(t+1) from hd(t):
// NT=32 (+guarded rep for tiles 32..39) x MT=8 x KS=2.
// ---------------------------------------------------------------------------
__global__ __launch_bounds__(256, 4) void dec_fused(
    const float* __restrict__ inputs, const f16* __restrict__ V,
    const float* __restrict__ W2, const float* __restrict__ b2,
    const f16* __restrict__ enchi,
    const float* __restrict__ fcW, const float* __restrict__ fcb,
    const float* __restrict__ Wih, const float* __restrict__ dbias,
    f16* __restrict__ gu, long long ustride,
    float* __restrict__ hc, f16* __restrict__ hdhi,
    const f16* __restrict__ dWchi, const f16* __restrict__ dWclo,
    const float* __restrict__ fcfW, const float* __restrict__ fcfb,
    float* __restrict__ out,
    unsigned* __restrict__ cntD, int t)
{
    __shared__ __align__(16) char smem[24576];
    int bid = blockIdx.x, tid = threadIdx.x;

    if (bid >= 512) {
        // ------------- consumer: gemm hd(t) @ dWc^T -> gu(t+1) -------------
        if (t >= TM1 - 1) return;
        int c = bid - 512;
        int nbase = c & 31, mt = (c >> 5) & 7, ks = c >> 8;
        if (tid == 0) {
            while (__hip_atomic_load(&cntD[t * 8 + mt], __ATOMIC_RELAXED,
                                     __HIP_MEMORY_SCOPE_AGENT) < 64u)
                __builtin_amdgcn_s_sleep(2);
        }
        __syncthreads();
#pragma unroll
        for (int rep = 0; rep < 2; ++rep) {
            int tile = nbase + rep * 32;
            if (tile >= 40) break;
            int n0 = tile * 64;
            int Kfull = (n0 >= 512) ? 512 : 1024;
            int ksz = Kfull >> 1;
            gemm_tile_aA(hdhi, 1024, dWchi, dWclo, 1024, dbias, ks == 0,
                         gu + (size_t)ks * ustride, 2560,
                         ks * ksz, ks * ksz + ksz, mt * 64, n0, smem);
        }
        return;
    }

    // ---------------- producer: dec_step for batch b ----------------
    float* su   = (float*)smem;               // 512 f
    float* sw2  = (float*)(smem + 2048);      // 512 f
    f16*   shf  = (f16*)(smem + 4096);        // 1024 h
    float* s_att= (float*)(smem + 6144);      // 32 f
    float* sred = (float*)(smem + 6272);      // 4 f
    int b = bid;
    const bool last = (t == TM1 - 1);

    {
        int e = tid * 2;
        float u0 = 0.f, u1 = 0.f;
        if (t > 0) {
            const f16* q = gu + (size_t)b * 2560 + e;
#pragma unroll
            for (int s = 0; s < 2; s++) {
                half2v a = *(const half2v*)(q + s * ustride);
                u0 += (float)a[0]; u1 += (float)a[1];
            }
        }
        su[e] = u0; su[e + 1] = u1;
        sw2[e] = W2[e]; sw2[e + 1] = W2[e + 1];
    }
    __syncthreads();
    if (tid < 248) {
        int tp = tid >> 3, l8 = tid & 7;
        const f16* vrow = V + ((size_t)b * TM1 + tp) * 512;
        float p = 0.f;
        for (int j = l8 * 8; j < 512; j += 64) {
            half8 v8 = *(const half8*)(vrow + j);
#pragma unroll
            for (int e = 0; e < 8; e++)
                p += tanh_fast(su[j + e] + (float)v8[e]) * sw2[j + e];
        }
        p += __shfl_xor(p, 1); p += __shfl_xor(p, 2); p += __shfl_xor(p, 4);
        if (l8 == 0) s_att[tp] = p + b2[0];
    }
    __syncthreads();
    if (tid < 64) {
        float v = (tid < TM1) ? s_att[tid] : -3.4e38f;
        float m = v;
#pragma unroll
        for (int k = 32; k > 0; k >>= 1) m = fmaxf(m, __shfl_xor(m, k));
        float e = (tid < TM1) ? __expf(v - m) : 0.f;
        float s = e;
#pragma unroll
        for (int k = 32; k > 0; k >>= 1) s += __shfl_xor(s, k);
        if (tid < TM1) s_att[tid] = e / s;
    }
    __syncthreads();

    float part = 0.f, pctx = 0.f;
#pragma unroll
    for (int r = 0; r < 2; r++) {
        int e = tid + r * 256;
        float cx = 0.f;
        const f16* eh = enchi + (size_t)b * TM1 * 512 + e;
        for (int tp = 0; tp < TM1; tp++)
            cx += s_att[tp] * (float)eh[tp * 512];
        part += cx * fcW[e];
        if (last) pctx += cx * fcfW[512 + e];
    }
    float y = inputs[((size_t)b * TM1 + t) * 257];
    float ysum = blockReduceSum256(part, sred);
    float y_til = ysum + y * fcW[512] + fcb[0];

    float ph = 0.f;
    {
        int e = tid * 2;
        float gi0, gi1, gf0, gf1, gg0, gg1, go0, go1;
        if (t > 0) {
            const f16* q = gu + (size_t)b * 2560 + e;
            gi0 = gi1 = gf0 = gf1 = gg0 = gg1 = go0 = go1 = 0.f;
#pragma unroll
            for (int s = 0; s < 2; s++) {
                const f16* qq = q + s * ustride;
                half2v a = *(const half2v*)(qq + 512);
                half2v f = *(const half2v*)(qq + 1024);
                half2v gv = *(const half2v*)(qq + 1536);
                half2v o = *(const half2v*)(qq + 2048);
                gi0 += (float)a[0]; gi1 += (float)a[1];
                gf0 += (float)f[0]; gf1 += (float)f[1];
                gg0 += (float)gv[0]; gg1 += (float)gv[1];
                go0 += (float)o[0]; go1 += (float)o[1];
            }
        } else {
            gi0 = dbias[512 + e];  gi1 = dbias[512 + e + 1];
            gf0 = dbias[1024 + e]; gf1 = dbias[1024 + e + 1];
            gg0 = dbias[1536 + e]; gg1 = dbias[1536 + e + 1];
            go0 = dbias[2048 + e]; go1 = dbias[2048 + e + 1];
        }
        gi0 += y_til * Wih[e];        gi1 += y_til * Wih[e + 1];
        gf0 += y_til * Wih[512 + e];  gf1 += y_til * Wih[512 + e + 1];
        gg0 += y_til * Wih[1024 + e]; gg1 += y_til * Wih[1024 + e + 1];
        go0 += y_til * Wih[1536 + e]; go1 += y_til * Wih[1536 + e + 1];
        float2 cpv = *(const float2*)(hc + b * 1024 + 512 + e);
        float c20 = sigmf(gf0) * cpv.x + sigmf(gi0) * tanh_fast(gg0);
        float c21 = sigmf(gf1) * cpv.y + sigmf(gi1) * tanh_fast(gg1);
        float h20 = sigmf(go0) * tanh_fast(c20);
        float h21 = sigmf(go1) * tanh_fast(c21);
        if (!last) {
            *(float2*)(hc + b * 1024 + e) = make_float2(h20, h21);
            *(float2*)(hc + b * 1024 + 512 + e) = make_float2(c20, c21);
            shf[e] = (f16)h20; shf[e + 1] = (f16)h21;
            shf[512 + e] = (f16)c20; shf[512 + e + 1] = (f16)c21;
        } else {
            ph += h20 * fcfW[e] + h21 * fcfW[e + 1];
        }
    }
    if (last) {
        float s = blockReduceSum256(ph + pctx, sred);
        if (tid == 0) out[b] = s + fcfb[0];
        return;
    }
    __syncthreads();
    st_agent((u64*)(hdhi + (size_t)b * 1024) + tid, *(const u64*)&shf[tid * 4]);
    __syncthreads();   // drains all waves' atomic stores
    if (tid == 0)
        __hip_atomic_fetch_add(&cntD[t * 8 + (b >> 6)], 1u,
                               __ATOMIC_RELEASE, __HIP_MEMORY_SCOPE_AGENT);
}

// ---------------------------------------------------------------------------
// V GEMM (unfused, all-normal loads): A row-major, NREP sweeps n-tiles.
// ---------------------------------------------------------------------------
__global__ __launch_bounds__(256) void gemm_v(
    const f16* __restrict__ Ahi, int lda,
    const f16* __restrict__ Whi, const f16* __restrict__ Wlo, int ldw,
    const float* __restrict__ bias, f16* __restrict__ C, int ldc,
    int K, int NT, int MT, int NREP)
{
    __shared__ f16 sAh[64 * 64];
    __shared__ f16 sWh[64 * 64];
    __shared__ f16 sWl[64 * 64];
    int tid = threadIdx.x, bid = blockIdx.x;
    int nbase = bid % NT;
    int m0 = ((bid / NT) % MT) * 64;
    int lane = tid & 63, wid = tid >> 6;
    int wm = wid >> 1, wn = wid & 1;
    int rl = lane & 31, kq = lane >> 5;
    int sr = tid >> 2;
    int g0 = (tid & 3) * 2;
    int s0 = sr * 64 + ((g0 ^ (sr & 7)) * 8);
    int s1 = sr * 64 + (((g0 + 1) ^ (sr & 7)) * 8);
    int arow = (wm * 32 + rl) * 64;
    int wrow = (wn * 32 + rl) * 64;
    int sw = (rl & 7);

    const f16* pAh = Ahi + (size_t)(m0 + sr) * lda + g0 * 8;

    for (int r = 0; r < NREP; ++r) {
        int n0 = (nbase + r * NT) * 64;
        const f16* pWh = Whi + (size_t)(n0 + sr) * ldw + g0 * 8;
        const f16* pWl = Wlo + (size_t)(n0 + sr) * ldw + g0 * 8;
        float4 rAh0 = *(const float4*)(pAh);
        float4 rAh1 = *(const float4*)(pAh + 8);
        float4 rWh0 = *(const float4*)(pWh);
        float4 rWh1 = *(const float4*)(pWh + 8);
        float4 rWl0 = *(const float4*)(pWl);
        float4 rWl1 = *(const float4*)(pWl + 8);
        floatx16 acc = {};
        for (int k0 = 0; k0 < K; k0 += 64) {
            __syncthreads();
            *(float4*)&sAh[s0] = rAh0; *(float4*)&sAh[s1] = rAh1;
            *(float4*)&sWh[s0] = rWh0; *(float4*)&sWh[s1] = rWh1;
            *(float4*)&sWl[s0] = rWl0; *(float4*)&sWl[s1] = rWl1;
            __syncthreads();
            int kn = k0 + 64;
            if (kn < K) {
                rAh0 = *(const float4*)(pAh + kn); rAh1 = *(const float4*)(pAh + kn + 8);
                rWh0 = *(const float4*)(pWh + kn); rWh1 = *(const float4*)(pWh + kn + 8);
                rWl0 = *(const float4*)(pWl + kn); rWl1 = *(const float4*)(pWl + kn + 8);
            }
#pragma unroll
            for (int kk = 0; kk < 64; kk += 16) {
                int lg = (kk >> 3) + kq;
                int off = ((lg ^ sw) * 8);
                half8 ah = *(const half8*)&sAh[arow + off];
                half8 wh = *(const half8*)&sWh[wrow + off];
                half8 wl = *(const half8*)&sWl[wrow + off];
                acc = __builtin_amdgcn_mfma_f32_32x32x16_f16(ah, wh, acc, 0, 0, 0);
                acc = __builtin_amdgcn_mfma_f32_32x32x16_f16(ah, wl, acc, 0, 0, 0);
            }
        }
        int col = n0 + wn * 32 + rl;
        float bv = bias[col];
#pragma unroll
        for (int rr = 0; rr < 16; ++rr) {
            int row = m0 + wm * 32 + (rr & 3) + 8 * (rr >> 2) + 4 * kq;
            C[(size_t)row * ldc + col] = (f16)(acc[rr] + bv);
        }
    }
}

extern "C" void kernel_launch(void* const* d_in, const int* in_sizes, int n_in,
                              void* d_out, int out_size, void* d_ws, size_t ws_size,
                              hipStream_t stream) {
    const float* inputs  = (const float*)d_in[0];
    const float* eWih    = (const float*)d_in[1];
    const float* eWhh    = (const float*)d_in[2];
    const float* ebih    = (const float*)d_in[3];
    const float* ebhh    = (const float*)d_in[4];
    const float* eWc     = (const float*)d_in[5];
    const float* ebc     = (const float*)d_in[6];
    const float* eWd     = (const float*)d_in[7];
    const float* ebd     = (const float*)d_in[8];
    const float* eWa     = (const float*)d_in[9];
    const float* eba     = (const float*)d_in[10];
    const float* dW1     = (const float*)d_in[11];
    const float* db1     = (const float*)d_in[12];
    const float* dW2     = (const float*)d_in[13];
    const float* db2     = (const float*)d_in[14];
    const float* dWih    = (const float*)d_in[15];
    const float* dWhh    = (const float*)d_in[16];
    const float* dbih    = (const float*)d_in[17];
    const float* dbhh    = (const float*)d_in[18];
    const float* fcW     = (const float*)d_in[19];
    const float* fcb     = (const float*)d_in[20];
    const float* fcfW    = (const float*)d_in[21];
    const float* fcfb    = (const float*)d_in[22];
    float* out = (float*)d_out;

    float* scr = (float*)d_ws;
    // ---- union A: t2s f16 (enc) | V f16 (dec) ----
    f16* t2s = (f16*)scr;                       // 4,063,232 h
    f16* Vf  = (f16*)scr;                       // 8,126,464 h
    // ---- union B: g slices (enc) | gu slices (dec), KS=2 ----
    f16* g0e = (f16*)(scr + 4063232);           // 2 x 1,048,576 h
    f16* gu0 = (f16*)(scr + 4063232);           // 2 x 1,310,720 h
    // ---- dedicated ----
    float* hc_enc = scr + 6684672;              //   524,288 f
    f16*   Ahi    = (f16*)(scr + 7208960);      //   393,216 h
    float* hc_dec = scr + 7405568;              //   524,288 f
    f16*   hdhi   = (f16*)(scr + 7929856);      //   524,288 h
    // ---- persistent ----
    f16* fp = (f16*)(scr + 8192000);
    f16* eWhi  = fp;             fp += 1572864;
    f16* eWlo  = fp;             fp += 1572864;
    f16* dWchi = fp;             fp += 2621440;
    f16* dWclo = fp;             fp += 2621440;
    f16* Vwhi  = fp;             fp += 262144;
    f16* Vwlo  = fp;             fp += 262144;
    f16* enchi = fp;             fp += 8126464;
    float* ebcomb = (float*)(((uintptr_t)fp + 15) & ~(uintptr_t)15);
    float* dbias  = ebcomb + 2048;              // 2560 f
    unsigned* cnt = (unsigned*)(dbias + 2560);  // 512 u32: cntE[256] | cntD[256]
    unsigned* cntE = cnt;
    unsigned* cntD = cnt + 256;

    hipLaunchKernelGGL(prep_t2s_kernel, dim3(512), dim3(256), 0, stream,
                       inputs, eWih, eWhh, ebih, ebhh, dW1, dWhh, dbih, dbhh,
                       eWd, ebd, eWhi, eWlo, dWchi, dWclo, Vwhi, Vwlo,
                       ebcomb, dbias, t2s, cnt);

    const long long gstride = 1048576;   // halves per g slice
    const long long ustride = 1310720;   // halves per gu slice

    // -------- encoder: fused producer+consumer per step --------
    for (int t = 0; t < TM1; t++) {
        hipLaunchKernelGGL(enc_fused, dim3(1024), dim3(256), 0, stream,
                           inputs, t2s, eWc, ebc, eWa, eba, g0e, gstride, hc_enc,
                           Ahi, enchi, hc_dec, eWhi, eWlo, ebcomb, cntE, t);
    }
    // finalize last LSTM step (producers only)
    hipLaunchKernelGGL(enc_fused, dim3(512), dim3(256), 0, stream,
                       inputs, t2s, eWc, ebc, eWa, eba, g0e, gstride, hc_enc,
                       Ahi, enchi, hc_dec, eWhi, eWlo, ebcomb, cntE, TM1);

    // -------- V = enc_out @ dec_W1[:,1024:]^T + b1 (f16 out) --------
    hipLaunchKernelGGL(gemm_v, dim3(992), dim3(256), 0, stream,
                       enchi, 512, Vwhi, Vwlo, 512, db1,
                       Vf, 512, 512, 4, 248, 2);

    // -------- decoder: fused producer+consumer per step --------
    for (int t = 0; t < TM1 - 1; t++) {
        hipLaunchKernelGGL(dec_fused, dim3(1024), dim3(256), 0, stream,
                           inputs, Vf, dW2, db2, enchi, fcW, fcb, dWih, dbias,
                           gu0, ustride, hc_dec, hdhi, dWchi, dWclo,
                           fcfW, fcfb, out, cntD, t);
    }
    // last step: producers only (fused final FC)
    hipLaunchKernelGGL(dec_fused, dim3(512), dim3(256), 0, stream,
                       inputs, Vf, dW2, db2, enchi, fcW, fcb, dWih, dbias,
                       gu0, ustride, hc_dec, hdhi, dWchi, dWclo,
                       fcfW, fcfb, out, cntD, TM1 - 1);
}

// Round 12
// 1597.541 us; speedup vs baseline: 2.6315x; 2.6315x over previous
//
#include <hip/hip_runtime.h>
#include <math.h>

#define BATCH 512
#define TM1   31
#define DIMD  256

typedef _Float16 f16;
typedef _Float16 half2v __attribute__((ext_vector_type(2)));
typedef _Float16 half8 __attribute__((ext_vector_type(8)));
typedef float floatx16 __attribute__((ext_vector_type(16)));

__device__ __forceinline__ float sigmf(float x) { return 1.f / (1.f + __expf(-x)); }

__device__ __forceinline__ float tanh_fast(float x) {
    float ax = fabsf(x);
    float t  = __expf(-2.f * ax);
    float r  = (1.f - t) / (1.f + t);
    return copysignf(r, x);
}

__device__ __forceinline__ void split16(float x, f16* hi, f16* lo) {
    f16 h = (f16)x;
    *hi = h;
    *lo = (f16)(x - (float)h);
}

__device__ __forceinline__ float blockReduceSum256(float v, float* sred) {
#pragma unroll
    for (int m = 32; m > 0; m >>= 1) v += __shfl_xor(v, m);
    __syncthreads();
    if ((threadIdx.x & 63) == 0) sred[threadIdx.x >> 6] = v;
    __syncthreads();
    return sred[0] + sred[1] + sred[2] + sred[3];
}

__device__ __forceinline__ float blockReduceMax256(float v, float* sred) {
#pragma unroll
    for (int m = 32; m > 0; m >>= 1) v = fmaxf(v, __shfl_xor(v, m));
    __syncthreads();
    if ((threadIdx.x & 63) == 0) sred[threadIdx.x >> 6] = v;
    __syncthreads();
    return fmaxf(fmaxf(sred[0], sred[1]), fmaxf(sred[2], sred[3]));
}

// ---------------------------------------------------------------------------
// prep + t2s fused. Weight splits 8-wide vectorized. t2s f16; Wc -> f16.
// ---------------------------------------------------------------------------
__global__ __launch_bounds__(256) void prep_t2s_kernel(
    const float* __restrict__ inputs,
    const float* __restrict__ eWih, const float* __restrict__ eWhh,
    const float* __restrict__ ebih, const float* __restrict__ ebhh,
    const float* __restrict__ dW1,  const float* __restrict__ dWhh,
    const float* __restrict__ dbih, const float* __restrict__ dbhh,
    const float* __restrict__ Wd,   const float* __restrict__ bd,
    const float* __restrict__ Wc,
    f16* __restrict__ eWhi, f16* __restrict__ eWlo,
    f16* __restrict__ dWchi, f16* __restrict__ dWclo,
    f16* __restrict__ Vwhi, f16* __restrict__ Vwlo,
    float* __restrict__ ebcomb, float* __restrict__ dbias,
    f16* __restrict__ t2s, f16* __restrict__ Wcf)
{
    __shared__ float sX[TM1 * DIMD];
    __shared__ float sWd[TM1 * TM1];
    int b = blockIdx.x, tid = threadIdx.x;
    int idx = b * 256 + tid;
    const int stride = 512 * 256;

    // ---- t2s for batch b (f16 out) ----
    for (int i = tid; i < TM1 * DIMD; i += 256) {
        int tt = i >> 8, d = i & 255;
        sX[i] = inputs[((size_t)b * TM1 + tt) * 257 + 1 + d];
    }
    for (int i = tid; i < TM1 * TM1; i += 256) sWd[i] = Wd[i];
    __syncthreads();
    int d = tid;
    for (int s = 0; s < TM1; s++) {
        float acc = bd[s];
        for (int tt = 0; tt < TM1; tt++) acc += sX[tt * DIMD + d] * sWd[s * TM1 + tt];
        t2s[((size_t)b * TM1 + s) * DIMD + d] = (f16)acc;
    }

    // ---- eW split ----
    for (int g = idx; g < 2048 * 96; g += stride) {
        int n = g / 96, k0 = (g % 96) * 8;
        const float* src = (k0 < 256) ? (eWih + n * 256 + k0)
                                      : (eWhh + n * 512 + (k0 - 256));
        float4 v0 = *(const float4*)src;
        float4 v1 = *(const float4*)(src + 4);
        float vv[8] = {v0.x, v0.y, v0.z, v0.w, v1.x, v1.y, v1.z, v1.w};
        f16 hi[8], lo[8];
#pragma unroll
        for (int e = 0; e < 8; e++) split16(vv[e], &hi[e], &lo[e]);
        *(half8*)(eWhi + n * 768 + k0) = *(half8*)hi;
        *(half8*)(eWlo + n * 768 + k0) = *(half8*)lo;
    }
    // ---- dWc split ----
    for (int g = idx; g < 2560 * 128; g += stride) {
        int n = g >> 7, k0 = (g & 127) * 8;
        float vv[8] = {};
        if (n < 512) {
            const float* src = dW1 + n * 1536 + k0;
            float4 v0 = *(const float4*)src, v1 = *(const float4*)(src + 4);
            vv[0]=v0.x; vv[1]=v0.y; vv[2]=v0.z; vv[3]=v0.w;
            vv[4]=v1.x; vv[5]=v1.y; vv[6]=v1.z; vv[7]=v1.w;
        } else if (k0 < 512) {
            const float* src = dWhh + (n - 512) * 512 + k0;
            float4 v0 = *(const float4*)src, v1 = *(const float4*)(src + 4);
            vv[0]=v0.x; vv[1]=v0.y; vv[2]=v0.z; vv[3]=v0.w;
            vv[4]=v1.x; vv[5]=v1.y; vv[6]=v1.z; vv[7]=v1.w;
        }
        f16 hi[8], lo[8];
#pragma unroll
        for (int e = 0; e < 8; e++) split16(vv[e], &hi[e], &lo[e]);
        *(half8*)(dWchi + n * 1024 + k0) = *(half8*)hi;
        *(half8*)(dWclo + n * 1024 + k0) = *(half8*)lo;
    }
    // ---- Vw split ----
    for (int g = idx; g < 512 * 64; g += stride) {
        int n = g >> 6, k0 = (g & 63) * 8;
        const float* src = dW1 + n * 1536 + 1024 + k0;
        float4 v0 = *(const float4*)src, v1 = *(const float4*)(src + 4);
        float vv[8] = {v0.x, v0.y, v0.z, v0.w, v1.x, v1.y, v1.z, v1.w};
        f16 hi[8], lo[8];
#pragma unroll
        for (int e = 0; e < 8; e++) split16(vv[e], &hi[e], &lo[e]);
        *(half8*)(Vwhi + n * 512 + k0) = *(half8*)hi;
        *(half8*)(Vwlo + n * 512 + k0) = *(half8*)lo;
    }
    // ---- Wc -> f16 (31*1024 = 31744 = 3968 groups of 8) ----
    for (int g = idx; g < 3968; g += stride) {
        int k0 = g * 8;
        float4 v0 = *(const float4*)(Wc + k0);
        float4 v1 = *(const float4*)(Wc + k0 + 4);
        f16 h[8] = {(f16)v0.x, (f16)v0.y, (f16)v0.z, (f16)v0.w,
                    (f16)v1.x, (f16)v1.y, (f16)v1.z, (f16)v1.w};
        *(half8*)(Wcf + k0) = *(half8*)h;
    }
    for (int i = idx; i < 2048; i += stride) ebcomb[i] = ebih[i] + ebhh[i];
    for (int i = idx; i < 2560; i += stride)
        dbias[i] = (i < 512) ? 0.f : (dbih[i - 512] + dbhh[i - 512]);
}

// ---------------------------------------------------------------------------
// Step GEMM: fp16x2, split-K2, f16 out, BK=128 (halved barrier rounds vs R9).
// 64x64 tile, 4 waves of 32x32x16. XOR swizzle on 16-granule rows (key
// row&15): stores/reads ~2-way bank aliasing (free). Register prefetch of
// the next 128-k chunk (12 float4). grid: n=bid%NT, m=(bid/NT)%MT,
// ks=bid/(NT*MT); NT%8==0 -> XCD-pinned weight slices.
// Kfull = (n0>=nsplit) ? 512 : K; slice = Kfull/KS (%128==0).
// ---------------------------------------------------------------------------
__global__ __launch_bounds__(256) void gemm2f(
    const f16* __restrict__ Ahi, int lda,
    const f16* __restrict__ Whi, const f16* __restrict__ Wlo, int ldw,
    const float* __restrict__ bias, f16* __restrict__ C, int ldc,
    long long Cstride, int K, int nsplit, int NT, int MT, int KS)
{
    __shared__ f16 sAh[64 * 128];
    __shared__ f16 sWh[64 * 128];
    __shared__ f16 sWl[64 * 128];
    int tid = threadIdx.x, bid = blockIdx.x;
    int nbase = bid % NT;
    int m0 = ((bid / NT) % MT) * 64;
    int ks = bid / (NT * MT);
    int lane = tid & 63, wid = tid >> 6;
    int wm = wid >> 1, wn = wid & 1;
    int rl = lane & 31, kq = lane >> 5;

    int sr = tid >> 2;
    int gb = (tid & 3) * 4;
    int st0 = sr * 128 + (((gb + 0) ^ (sr & 15)) * 8);
    int st1 = sr * 128 + (((gb + 1) ^ (sr & 15)) * 8);
    int st2 = sr * 128 + (((gb + 2) ^ (sr & 15)) * 8);
    int st3 = sr * 128 + (((gb + 3) ^ (sr & 15)) * 8);
    int arow = (wm * 32 + rl) * 128;
    int wrow = (wn * 32 + rl) * 128;
    int swk = rl & 15;   // row&15 (wm*32 / wn*32 are multiples of 16)

    int n0 = nbase * 64;
    int Kfull = (n0 >= nsplit) ? 512 : K;
    int ksz = Kfull / KS;
    int kbeg = ks * ksz, kend = kbeg + ksz;

    const f16* pA  = Ahi + (size_t)(m0 + sr) * lda + gb * 8;
    const f16* pWh = Whi + (size_t)(n0 + sr) * ldw + gb * 8;
    const f16* pWl = Wlo + (size_t)(n0 + sr) * ldw + gb * 8;

    float4 rA0 = *(const float4*)(pA + kbeg);
    float4 rA1 = *(const float4*)(pA + kbeg + 8);
    float4 rA2 = *(const float4*)(pA + kbeg + 16);
    float4 rA3 = *(const float4*)(pA + kbeg + 24);
    float4 rH0 = *(const float4*)(pWh + kbeg);
    float4 rH1 = *(const float4*)(pWh + kbeg + 8);
    float4 rH2 = *(const float4*)(pWh + kbeg + 16);
    float4 rH3 = *(const float4*)(pWh + kbeg + 24);
    float4 rL0 = *(const float4*)(pWl + kbeg);
    float4 rL1 = *(const float4*)(pWl + kbeg + 8);
    float4 rL2 = *(const float4*)(pWl + kbeg + 16);
    float4 rL3 = *(const float4*)(pWl + kbeg + 24);

    floatx16 acc = {};
    for (int k0 = kbeg; k0 < kend; k0 += 128) {
        __syncthreads();
        *(float4*)&sAh[st0] = rA0; *(float4*)&sAh[st1] = rA1;
        *(float4*)&sAh[st2] = rA2; *(float4*)&sAh[st3] = rA3;
        *(float4*)&sWh[st0] = rH0; *(float4*)&sWh[st1] = rH1;
        *(float4*)&sWh[st2] = rH2; *(float4*)&sWh[st3] = rH3;
        *(float4*)&sWl[st0] = rL0; *(float4*)&sWl[st1] = rL1;
        *(float4*)&sWl[st2] = rL2; *(float4*)&sWl[st3] = rL3;
        __syncthreads();
        int kn = k0 + 128;
        if (kn < kend) {
            rA0 = *(const float4*)(pA + kn);      rA1 = *(const float4*)(pA + kn + 8);
            rA2 = *(const float4*)(pA + kn + 16); rA3 = *(const float4*)(pA + kn + 24);
            rH0 = *(const float4*)(pWh + kn);      rH1 = *(const float4*)(pWh + kn + 8);
            rH2 = *(const float4*)(pWh + kn + 16); rH3 = *(const float4*)(pWh + kn + 24);
            rL0 = *(const float4*)(pWl + kn);      rL1 = *(const float4*)(pWl + kn + 8);
            rL2 = *(const float4*)(pWl + kn + 16); rL3 = *(const float4*)(pWl + kn + 24);
        }
#pragma unroll
        for (int kk = 0; kk < 128; kk += 16) {
            int lg = (kk >> 3) + kq;
            half8 ah = *(const half8*)&sAh[arow + ((lg ^ swk) * 8)];
            half8 wh = *(const half8*)&sWh[wrow + ((lg ^ swk) * 8)];
            half8 wl = *(const half8*)&sWl[wrow + ((lg ^ swk) * 8)];
            acc = __builtin_amdgcn_mfma_f32_32x32x16_f16(ah, wh, acc, 0, 0, 0);
            acc = __builtin_amdgcn_mfma_f32_32x32x16_f16(ah, wl, acc, 0, 0, 0);
        }
    }

    int col = n0 + wn * 32 + rl;
    float bv = (ks == 0) ? bias[col] : 0.f;
    f16* Cp = C + (size_t)ks * Cstride;
#pragma unroll
    for (int rr = 0; rr < 16; ++rr) {
        int row = m0 + wm * 32 + (rr & 3) + 8 * (rr >> 2) + 4 * kq;
        Cp[(size_t)row * ldc + col] = (f16)(acc[rr] + bv);
    }
}

// ---------------------------------------------------------------------------
// V GEMM (R9-validated BK=64 path): NREP sweeps n-tiles reusing the A tile.
// ---------------------------------------------------------------------------
__global__ __launch_bounds__(256) void gemm_v(
    const f16* __restrict__ Ahi, int lda,
    const f16* __restrict__ Whi, const f16* __restrict__ Wlo, int ldw,
    const float* __restrict__ bias, f16* __restrict__ C, int ldc,
    int K, int NT, int MT, int NREP)
{
    __shared__ f16 sAh[64 * 64];
    __shared__ f16 sWh[64 * 64];
    __shared__ f16 sWl[64 * 64];
    int tid = threadIdx.x, bid = blockIdx.x;
    int nbase = bid % NT;
    int m0 = ((bid / NT) % MT) * 64;
    int lane = tid & 63, wid = tid >> 6;
    int wm = wid >> 1, wn = wid & 1;
    int rl = lane & 31, kq = lane >> 5;
    int sr = tid >> 2;
    int g0 = (tid & 3) * 2;
    int s0 = sr * 64 + ((g0 ^ (sr & 7)) * 8);
    int s1 = sr * 64 + (((g0 + 1) ^ (sr & 7)) * 8);
    int arow = (wm * 32 + rl) * 64;
    int wrow = (wn * 32 + rl) * 64;
    int sw = (rl & 7);

    const f16* pAh = Ahi + (size_t)(m0 + sr) * lda + g0 * 8;

    for (int r = 0; r < NREP; ++r) {
        int n0 = (nbase + r * NT) * 64;
        const f16* pWh = Whi + (size_t)(n0 + sr) * ldw + g0 * 8;
        const f16* pWl = Wlo + (size_t)(n0 + sr) * ldw + g0 * 8;
        float4 rAh0 = *(const float4*)(pAh);
        float4 rAh1 = *(const float4*)(pAh + 8);
        float4 rWh0 = *(const float4*)(pWh);
        float4 rWh1 = *(const float4*)(pWh + 8);
        float4 rWl0 = *(const float4*)(pWl);
        float4 rWl1 = *(const float4*)(pWl + 8);
        floatx16 acc = {};
        for (int k0 = 0; k0 < K; k0 += 64) {
            __syncthreads();
            *(float4*)&sAh[s0] = rAh0; *(float4*)&sAh[s1] = rAh1;
            *(float4*)&sWh[s0] = rWh0; *(float4*)&sWh[s1] = rWh1;
            *(float4*)&sWl[s0] = rWl0; *(float4*)&sWl[s1] = rWl1;
            __syncthreads();
            int kn = k0 + 64;
            if (kn < K) {
                rAh0 = *(const float4*)(pAh + kn); rAh1 = *(const float4*)(pAh + kn + 8);
                rWh0 = *(const float4*)(pWh + kn); rWh1 = *(const float4*)(pWh + kn + 8);
                rWl0 = *(const float4*)(pWl + kn); rWl1 = *(const float4*)(pWl + kn + 8);
            }
#pragma unroll
            for (int kk = 0; kk < 64; kk += 16) {
                int lg = (kk >> 3) + kq;
                int off = ((lg ^ sw) * 8);
                half8 ah = *(const half8*)&sAh[arow + off];
                half8 wh = *(const half8*)&sWh[wrow + off];
                half8 wl = *(const half8*)&sWl[wrow + off];
                acc = __builtin_amdgcn_mfma_f32_32x32x16_f16(ah, wh, acc, 0, 0, 0);
                acc = __builtin_amdgcn_mfma_f32_32x32x16_f16(ah, wl, acc, 0, 0, 0);
            }
        }
        int col = n0 + wn * 32 + rl;
        float bv = bias[col];
#pragma unroll
        for (int rr = 0; rr < 16; ++rr) {
            int row = m0 + wm * 32 + (rr & 3) + 8 * (rr >> 2) + 4 * kq;
            C[(size_t)row * ldc + col] = (f16)(acc[rr] + bv);
        }
    }
}

// ---------------------------------------------------------------------------
// Encoder step: 512 blocks, one batch per block. Finalize LSTM t-1 from 2
// f16 g-slices (half2 loads), then attention t (f16 t2s, f16 Wc).
// ---------------------------------------------------------------------------
__global__ __launch_bounds__(256) void enc_step_kernel(
    const float* __restrict__ inputs, const f16* __restrict__ t2s,
    const f16* __restrict__ Wcf, const float* __restrict__ bc,
    const float* __restrict__ Wa, const float* __restrict__ ba,
    const f16* __restrict__ g, long long gstride,
    float* __restrict__ hc,
    f16* __restrict__ Ahi, f16* __restrict__ enchi,
    float* __restrict__ hc_dec, f16* __restrict__ hdhi,
    int t) {
    __shared__ float sh_hc[1024];
    __shared__ float t1s[32];
    __shared__ float sred[4];
    int b = blockIdx.x, tid = threadIdx.x;

    if (t > 0) {
        int e = tid * 2;
        const f16* gp = g + (size_t)b * 2048 + e;
        float gi0 = 0.f, gi1 = 0.f, gf0 = 0.f, gf1 = 0.f;
        float gg0 = 0.f, gg1 = 0.f, go0 = 0.f, go1 = 0.f;
#pragma unroll
        for (int s = 0; s < 2; s++) {
            const f16* q = gp + s * gstride;
            half2v a = *(const half2v*)(q);
            half2v f = *(const half2v*)(q + 512);
            half2v gv = *(const half2v*)(q + 1024);
            half2v o = *(const half2v*)(q + 1536);
            gi0 += (float)a[0]; gi1 += (float)a[1];
            gf0 += (float)f[0]; gf1 += (float)f[1];
            gg0 += (float)gv[0]; gg1 += (float)gv[1];
            go0 += (float)o[0]; go1 += (float)o[1];
        }
        float2 cpv = *(const float2*)(hc + b * 1024 + 512 + e);
        float c20 = sigmf(gf0) * cpv.x + sigmf(gi0) * tanh_fast(gg0);
        float c21 = sigmf(gf1) * cpv.y + sigmf(gi1) * tanh_fast(gg1);
        float h20 = sigmf(go0) * tanh_fast(c20);
        float h21 = sigmf(go1) * tanh_fast(c21);
        *(float2*)(hc + b * 1024 + e) = make_float2(h20, h21);
        *(float2*)(hc + b * 1024 + 512 + e) = make_float2(c20, c21);
        sh_hc[e] = h20; sh_hc[e + 1] = h21;
        sh_hc[512 + e] = c20; sh_hc[512 + e + 1] = c21;
        half2v hv; hv[0] = (f16)h20; hv[1] = (f16)h21;
        *(half2v*)(enchi + ((size_t)b * TM1 + (t - 1)) * 512 + e) = hv;
    } else {
        for (int j = tid; j < 1024; j += 256) { sh_hc[j] = 0.f; hc[b * 1024 + j] = 0.f; }
    }
    if (t == TM1) {
        for (int j = tid; j < 1024; j += 256) {
            hc_dec[b * 1024 + j] = 0.f;
            hdhi[b * 1024 + j] = (f16)0.f;
        }
        return;
    }
    __syncthreads();

    if (tid < 248) {
        int s = tid >> 3, l8 = tid & 7;
        const f16* wrow = Wcf + s * 1024;
        float p = 0.f;
        for (int j = l8 * 8; j < 1024; j += 64) {
            half8 w8 = *(const half8*)(wrow + j);
#pragma unroll
            for (int e = 0; e < 8; e++) p += (float)w8[e] * sh_hc[j + e];
        }
        p += __shfl_xor(p, 1); p += __shfl_xor(p, 2); p += __shfl_xor(p, 4);
        if (l8 == 0) t1s[s] = p + bc[s];
    }
    __syncthreads();

    int d = tid;
    float sc = ba[0];
    const f16* t2p = t2s + ((size_t)b * TM1) * DIMD + d;
    for (int s = 0; s < TM1; s++) sc += tanh_fast(t1s[s] + (float)t2p[s * DIMD]) * Wa[s];
    float mx = blockReduceMax256(sc, sred);
    float ex = __expf(sc - mx);
    float sm = blockReduceSum256(ex, sred);
    float w = (ex / sm) * inputs[((size_t)b * TM1 + t) * 257 + 1 + d];
    Ahi[b * 768 + d] = (f16)w;
    for (int j = tid; j < 512; j += 256)
        Ahi[b * 768 + 256 + j] = (f16)sh_hc[j];
}

// ---------------------------------------------------------------------------
// Decoder step: attention (f16 V) + ctx + y_tilde + LSTM pointwise from 2
// f16 gu-slices (half2 loads). Last step fuses final FC.
// ---------------------------------------------------------------------------
__global__ __launch_bounds__(256) void dec_step_kernel(
    const float* __restrict__ inputs, const f16* __restrict__ V,
    const float* __restrict__ W2, const float* __restrict__ b2,
    const f16* __restrict__ enchi,
    const float* __restrict__ fcW, const float* __restrict__ fcb,
    const float* __restrict__ Wih,
    const f16* __restrict__ gu, long long ustride,
    float* __restrict__ hc, f16* __restrict__ hdhi,
    const float* __restrict__ fcfW, const float* __restrict__ fcfb,
    float* __restrict__ out, int t) {
    __shared__ float su[512];
    __shared__ float sw2[512];
    __shared__ float s_att[TM1];
    __shared__ float sred[4];
    int b = blockIdx.x, tid = threadIdx.x;
    const bool last = (t == TM1 - 1);
    {
        int e = tid * 2;
        const f16* q = gu + (size_t)b * 2560 + e;
        half2v a0 = *(const half2v*)(q);
        half2v a1 = *(const half2v*)(q + ustride);
        su[e]     = (float)a0[0] + (float)a1[0];
        su[e + 1] = (float)a0[1] + (float)a1[1];
        sw2[e] = W2[e]; sw2[e + 1] = W2[e + 1];
    }
    __syncthreads();
    if (tid < 248) {
        int tp = tid >> 3, l8 = tid & 7;
        const f16* vrow = V + ((size_t)b * TM1 + tp) * 512;
        float p = 0.f;
        for (int j = l8 * 8; j < 512; j += 64) {
            half8 v8 = *(const half8*)(vrow + j);
#pragma unroll
            for (int e = 0; e < 8; e++)
                p += tanh_fast(su[j + e] + (float)v8[e]) * sw2[j + e];
        }
        p += __shfl_xor(p, 1); p += __shfl_xor(p, 2); p += __shfl_xor(p, 4);
        if (l8 == 0) s_att[tp] = p + b2[0];
    }
    __syncthreads();
    if (tid < 64) {
        float v = (tid < TM1) ? s_att[tid] : -3.4e38f;
        float m = v;
#pragma unroll
        for (int k = 32; k > 0; k >>= 1) m = fmaxf(m, __shfl_xor(m, k));
        float e = (tid < TM1) ? __expf(v - m) : 0.f;
        float s = e;
#pragma unroll
        for (int k = 32; k > 0; k >>= 1) s += __shfl_xor(s, k);
        if (tid < TM1) s_att[tid] = e / s;
    }
    __syncthreads();

    float part = 0.f;
    float pctx = 0.f;
#pragma unroll
    for (int r = 0; r < 2; r++) {
        int e = tid + r * 256;
        float cx = 0.f;
        const f16* eh = enchi + (size_t)b * TM1 * 512 + e;
        for (int tp = 0; tp < TM1; tp++)
            cx += s_att[tp] * (float)eh[tp * 512];
        part += cx * fcW[e];
        if (last) pctx += cx * fcfW[512 + e];
    }
    float y = inputs[((size_t)b * TM1 + t) * 257];
    float ysum = blockReduceSum256(part, sred);
    float y_til = ysum + y * fcW[512] + fcb[0];

    float ph = 0.f;
    {
        int e = tid * 2;
        const f16* q = gu + (size_t)b * 2560 + e;
        float gi0 = 0.f, gi1 = 0.f, gf0 = 0.f, gf1 = 0.f;
        float gg0 = 0.f, gg1 = 0.f, go0 = 0.f, go1 = 0.f;
#pragma unroll
        for (int s = 0; s < 2; s++) {
            const f16* qq = q + s * ustride;
            half2v a = *(const half2v*)(qq + 512);
            half2v f = *(const half2v*)(qq + 1024);
            half2v gv = *(const half2v*)(qq + 1536);
            half2v o = *(const half2v*)(qq + 2048);
            gi0 += (float)a[0]; gi1 += (float)a[1];
            gf0 += (float)f[0]; gf1 += (float)f[1];
            gg0 += (float)gv[0]; gg1 += (float)gv[1];
            go0 += (float)o[0]; go1 += (float)o[1];
        }
        gi0 += y_til * Wih[e];        gi1 += y_til * Wih[e + 1];
        gf0 += y_til * Wih[512 + e];  gf1 += y_til * Wih[512 + e + 1];
        gg0 += y_til * Wih[1024 + e]; gg1 += y_til * Wih[1024 + e + 1];
        go0 += y_til * Wih[1536 + e]; go1 += y_til * Wih[1536 + e + 1];
        float2 cpv = *(const float2*)(hc + b * 1024 + 512 + e);
        float c20 = sigmf(gf0) * cpv.x + sigmf(gi0) * tanh_fast(gg0);
        float c21 = sigmf(gf1) * cpv.y + sigmf(gi1) * tanh_fast(gg1);
        float h20 = sigmf(go0) * tanh_fast(c20);
        float h21 = sigmf(go1) * tanh_fast(c21);
        if (!last) {
            *(float2*)(hc + b * 1024 + e) = make_float2(h20, h21);
            *(float2*)(hc + b * 1024 + 512 + e) = make_float2(c20, c21);
            half2v hv; hv[0] = (f16)h20; hv[1] = (f16)h21;
            half2v cv; cv[0] = (f16)c20; cv[1] = (f16)c21;
            *(half2v*)(hdhi + (size_t)b * 1024 + e) = hv;
            *(half2v*)(hdhi + (size_t)b * 1024 + 512 + e) = cv;
        } else {
            ph += h20 * fcfW[e] + h21 * fcfW[e + 1];
        }
    }
    if (last) {
        float s = blockReduceSum256(ph + pctx, sred);
        if (tid == 0) out[b] = s + fcfb[0];
    }
}

extern "C" void kernel_launch(void* const* d_in, const int* in_sizes, int n_in,
                              void* d_out, int out_size, void* d_ws, size_t ws_size,
                              hipStream_t stream) {
    const float* inputs  = (const float*)d_in[0];
    const float* eWih    = (const float*)d_in[1];
    const float* eWhh    = (const float*)d_in[2];
    const float* ebih    = (const float*)d_in[3];
    const float* ebhh    = (const float*)d_in[4];
    const float* eWc     = (const float*)d_in[5];
    const float* ebc     = (const float*)d_in[6];
    const float* eWd     = (const float*)d_in[7];
    const float* ebd     = (const float*)d_in[8];
    const float* eWa     = (const float*)d_in[9];
    const float* eba     = (const float*)d_in[10];
    const float* dW1     = (const float*)d_in[11];
    const float* db1     = (const float*)d_in[12];
    const float* dW2     = (const float*)d_in[13];
    const float* db2     = (const float*)d_in[14];
    const float* dWih    = (const float*)d_in[15];
    const float* dWhh    = (const float*)d_in[16];
    const float* dbih    = (const float*)d_in[17];
    const float* dbhh    = (const float*)d_in[18];
    const float* fcW     = (const float*)d_in[19];
    const float* fcb     = (const float*)d_in[20];
    const float* fcfW    = (const float*)d_in[21];
    const float* fcfb    = (const float*)d_in[22];
    float* out = (float*)d_out;

    float* scr = (float*)d_ws;
    // ---- union A: t2s f16 (enc) | V f16 (dec) ----
    f16* t2s = (f16*)scr;                       // 4,063,232 h
    f16* Vf  = (f16*)scr;                       // 8,126,464 h
    // ---- union B: g slices (enc) | gu slices (dec), KS=2 ----
    f16* g0e = (f16*)(scr + 4063232);           // 2 x 1,048,576 h
    f16* gu0 = (f16*)(scr + 4063232);           // 2 x 1,310,720 h
    // ---- dedicated ----
    float* hc_enc = scr + 6684672;              //   524,288 f
    f16*   Ahi    = (f16*)(scr + 7208960);      //   393,216 h
    float* hc_dec = scr + 7405568;              //   524,288 f
    f16*   hdhi   = (f16*)(scr + 7929856);      //   524,288 h
    // ---- persistent ----
    f16* fp = (f16*)(scr + 8192000);
    f16* eWhi  = fp;             fp += 1572864;
    f16* eWlo  = fp;             fp += 1572864;
    f16* dWchi = fp;             fp += 2621440;
    f16* dWclo = fp;             fp += 2621440;
    f16* Vwhi  = fp;             fp += 262144;
    f16* Vwlo  = fp;             fp += 262144;
    f16* enchi = fp;             fp += 8126464;
    float* ebcomb = (float*)(((uintptr_t)fp + 15) & ~(uintptr_t)15);
    float* dbias  = ebcomb + 2048;              // 2560 f
    f16* Wcf = (f16*)(dbias + 2560);            // 31,744 h

    hipLaunchKernelGGL(prep_t2s_kernel, dim3(512), dim3(256), 0, stream,
                       inputs, eWih, eWhh, ebih, ebhh, dW1, dWhh, dbih, dbhh,
                       eWd, ebd, eWc, eWhi, eWlo, dWchi, dWclo, Vwhi, Vwlo,
                       ebcomb, dbias, t2s, Wcf);

    const long long gstride = 1048576;   // halves per g slice
    const long long ustride = 1310720;   // halves per gu slice

    // -------- encoder --------
    for (int t = 0; t < TM1; t++) {
        hipLaunchKernelGGL(enc_step_kernel, dim3(BATCH), dim3(256), 0, stream,
                           inputs, t2s, Wcf, ebc, eWa, eba, g0e, gstride, hc_enc,
                           Ahi, enchi, hc_dec, hdhi, t);
        // M=512,N=2048,K=768 split-K2 BK=128: NT=32, MT=8, KS=2 -> 512 blocks
        hipLaunchKernelGGL(gemm2f, dim3(512), dim3(256), 0, stream,
                           Ahi, 768, eWhi, eWlo, 768, ebcomb,
                           g0e, 2048, gstride, 768, 1 << 30, 32, 8, 2);
    }
    hipLaunchKernelGGL(enc_step_kernel, dim3(BATCH), dim3(256), 0, stream,
                       inputs, t2s, Wcf, ebc, eWa, eba, g0e, gstride, hc_enc,
                       Ahi, enchi, hc_dec, hdhi, TM1);

    // -------- V = enc_out @ dec_W1[:,1024:]^T + b1 (f16 out) --------
    hipLaunchKernelGGL(gemm_v, dim3(992), dim3(256), 0, stream,
                       enchi, 512, Vwhi, Vwlo, 512, db1,
                       Vf, 512, 512, 4, 248, 2);

    // -------- decoder --------
    for (int t = 0; t < TM1; t++) {
        // M=512,N=2560 split-K2 BK=128: NT=40, MT=8, KS=2 -> 640 blocks
        hipLaunchKernelGGL(gemm2f, dim3(640), dim3(256), 0, stream,
                           hdhi, 1024, dWchi, dWclo, 1024, dbias,
                           gu0, 2560, ustride, 1024, 512, 40, 8, 2);
        hipLaunchKernelGGL(dec_step_kernel, dim3(BATCH), dim3(256), 0, stream,
                           inputs, Vf, dW2, db2, enchi, fcW, fcb, dWih,
                           gu0, ustride, hc_dec, hdhi, fcfW, fcfb, out, t);
    }
}

// Round 13
// 1445.114 us; speedup vs baseline: 2.9090x; 1.1055x over previous
//
#include <hip/hip_runtime.h>
#include <math.h>

#define BATCH 512
#define TM1   31
#define DIMD  256

typedef _Float16 f16;
typedef _Float16 half2v __attribute__((ext_vector_type(2)));
typedef _Float16 half8 __attribute__((ext_vector_type(8)));
typedef float floatx16 __attribute__((ext_vector_type(16)));

__device__ __forceinline__ float sigmf(float x) { return 1.f / (1.f + __expf(-x)); }

__device__ __forceinline__ float tanh_fast(float x) {
    float ax = fabsf(x);
    float t  = __expf(-2.f * ax);
    float r  = (1.f - t) / (1.f + t);
    return copysignf(r, x);
}

__device__ __forceinline__ float blockReduceSum256(float v, float* sred) {
#pragma unroll
    for (int m = 32; m > 0; m >>= 1) v += __shfl_xor(v, m);
    __syncthreads();
    if ((threadIdx.x & 63) == 0) sred[threadIdx.x >> 6] = v;
    __syncthreads();
    return sred[0] + sred[1] + sred[2] + sred[3];
}

__device__ __forceinline__ float blockReduceMax256(float v, float* sred) {
#pragma unroll
    for (int m = 32; m > 0; m >>= 1) v = fmaxf(v, __shfl_xor(v, m));
    __syncthreads();
    if ((threadIdx.x & 63) == 0) sred[threadIdx.x >> 6] = v;
    __syncthreads();
    return fmaxf(fmaxf(sred[0], sred[1]), fmaxf(sred[2], sred[3]));
}

// ---------------------------------------------------------------------------
// prep + t2s fused. Pure-f16 weight conversion (no hi/lo split — R13).
// ---------------------------------------------------------------------------
__global__ __launch_bounds__(256) void prep_t2s_kernel(
    const float* __restrict__ inputs,
    const float* __restrict__ eWih, const float* __restrict__ eWhh,
    const float* __restrict__ ebih, const float* __restrict__ ebhh,
    const float* __restrict__ dW1,  const float* __restrict__ dWhh,
    const float* __restrict__ dbih, const float* __restrict__ dbhh,
    const float* __restrict__ Wd,   const float* __restrict__ bd,
    const float* __restrict__ Wc,
    f16* __restrict__ eWf, f16* __restrict__ dWcf, f16* __restrict__ Vwf,
    float* __restrict__ ebcomb, float* __restrict__ dbias,
    f16* __restrict__ t2s, f16* __restrict__ Wcf)
{
    __shared__ float sX[TM1 * DIMD];
    __shared__ float sWd[TM1 * TM1];
    int b = blockIdx.x, tid = threadIdx.x;
    int idx = b * 256 + tid;
    const int stride = 512 * 256;

    // ---- t2s for batch b (f16 out) ----
    for (int i = tid; i < TM1 * DIMD; i += 256) {
        int tt = i >> 8, d = i & 255;
        sX[i] = inputs[((size_t)b * TM1 + tt) * 257 + 1 + d];
    }
    for (int i = tid; i < TM1 * TM1; i += 256) sWd[i] = Wd[i];
    __syncthreads();
    int d = tid;
    for (int s = 0; s < TM1; s++) {
        float acc = bd[s];
        for (int tt = 0; tt < TM1; tt++) acc += sX[tt * DIMD + d] * sWd[s * TM1 + tt];
        t2s[((size_t)b * TM1 + s) * DIMD + d] = (f16)acc;
    }

    // ---- eW -> f16 ----
    for (int g = idx; g < 2048 * 96; g += stride) {
        int n = g / 96, k0 = (g % 96) * 8;
        const float* src = (k0 < 256) ? (eWih + n * 256 + k0)
                                      : (eWhh + n * 512 + (k0 - 256));
        float4 v0 = *(const float4*)src;
        float4 v1 = *(const float4*)(src + 4);
        f16 h[8] = {(f16)v0.x, (f16)v0.y, (f16)v0.z, (f16)v0.w,
                    (f16)v1.x, (f16)v1.y, (f16)v1.z, (f16)v1.w};
        *(half8*)(eWf + n * 768 + k0) = *(half8*)h;
    }
    // ---- dWc -> f16 ----
    for (int g = idx; g < 2560 * 128; g += stride) {
        int n = g >> 7, k0 = (g & 127) * 8;
        float vv[8] = {};
        if (n < 512) {
            const float* src = dW1 + n * 1536 + k0;
            float4 v0 = *(const float4*)src, v1 = *(const float4*)(src + 4);
            vv[0]=v0.x; vv[1]=v0.y; vv[2]=v0.z; vv[3]=v0.w;
            vv[4]=v1.x; vv[5]=v1.y; vv[6]=v1.z; vv[7]=v1.w;
        } else if (k0 < 512) {
            const float* src = dWhh + (n - 512) * 512 + k0;
            float4 v0 = *(const float4*)src, v1 = *(const float4*)(src + 4);
            vv[0]=v0.x; vv[1]=v0.y; vv[2]=v0.z; vv[3]=v0.w;
            vv[4]=v1.x; vv[5]=v1.y; vv[6]=v1.z; vv[7]=v1.w;
        }
        f16 h[8];
#pragma unroll
        for (int e = 0; e < 8; e++) h[e] = (f16)vv[e];
        *(half8*)(dWcf + n * 1024 + k0) = *(half8*)h;
    }
    // ---- Vw -> f16 ----
    for (int g = idx; g < 512 * 64; g += stride) {
        int n = g >> 6, k0 = (g & 63) * 8;
        const float* src = dW1 + n * 1536 + 1024 + k0;
        float4 v0 = *(const float4*)src, v1 = *(const float4*)(src + 4);
        f16 h[8] = {(f16)v0.x, (f16)v0.y, (f16)v0.z, (f16)v0.w,
                    (f16)v1.x, (f16)v1.y, (f16)v1.z, (f16)v1.w};
        *(half8*)(Vwf + n * 512 + k0) = *(half8*)h;
    }
    // ---- Wc -> f16 ----
    for (int g = idx; g < 3968; g += stride) {
        int k0 = g * 8;
        float4 v0 = *(const float4*)(Wc + k0);
        float4 v1 = *(const float4*)(Wc + k0 + 4);
        f16 h[8] = {(f16)v0.x, (f16)v0.y, (f16)v0.z, (f16)v0.w,
                    (f16)v1.x, (f16)v1.y, (f16)v1.z, (f16)v1.w};
        *(half8*)(Wcf + k0) = *(half8*)h;
    }
    for (int i = idx; i < 2048; i += stride) ebcomb[i] = ebih[i] + ebhh[i];
    for (int i = idx; i < 2560; i += stride)
        dbias[i] = (i < 512) ? 0.f : (dbih[i - 512] + dbhh[i - 512]);
}

// ---------------------------------------------------------------------------
// Step GEMM: pure-f16 weights, split-K2, f16 out, BK=128 (R12-validated
// structure, one MFMA per kk). 64x64 tile, 4 waves of 32x32x16. XOR swizzle
// on 16-granule rows (row&15). Register prefetch of next 128-k chunk.
// grid: n=bid%NT, m=(bid/NT)%MT, ks=bid/(NT*MT); NT%8==0 -> XCD-pinned W.
// ---------------------------------------------------------------------------
__global__ __launch_bounds__(256) void gemm1f(
    const f16* __restrict__ A, int lda,
    const f16* __restrict__ W, int ldw,
    const float* __restrict__ bias, f16* __restrict__ C, int ldc,
    long long Cstride, int K, int nsplit, int NT, int MT, int KS)
{
    __shared__ f16 sAh[64 * 128];
    __shared__ f16 sWh[64 * 128];
    int tid = threadIdx.x, bid = blockIdx.x;
    int nbase = bid % NT;
    int m0 = ((bid / NT) % MT) * 64;
    int ks = bid / (NT * MT);
    int lane = tid & 63, wid = tid >> 6;
    int wm = wid >> 1, wn = wid & 1;
    int rl = lane & 31, kq = lane >> 5;

    int sr = tid >> 2;
    int gb = (tid & 3) * 4;
    int st0 = sr * 128 + (((gb + 0) ^ (sr & 15)) * 8);
    int st1 = sr * 128 + (((gb + 1) ^ (sr & 15)) * 8);
    int st2 = sr * 128 + (((gb + 2) ^ (sr & 15)) * 8);
    int st3 = sr * 128 + (((gb + 3) ^ (sr & 15)) * 8);
    int arow = (wm * 32 + rl) * 128;
    int wrow = (wn * 32 + rl) * 128;
    int swk = rl & 15;

    int n0 = nbase * 64;
    int Kfull = (n0 >= nsplit) ? 512 : K;
    int ksz = Kfull / KS;
    int kbeg = ks * ksz, kend = kbeg + ksz;

    const f16* pA = A + (size_t)(m0 + sr) * lda + gb * 8;
    const f16* pW = W + (size_t)(n0 + sr) * ldw + gb * 8;

    float4 rA0 = *(const float4*)(pA + kbeg);
    float4 rA1 = *(const float4*)(pA + kbeg + 8);
    float4 rA2 = *(const float4*)(pA + kbeg + 16);
    float4 rA3 = *(const float4*)(pA + kbeg + 24);
    float4 rW0 = *(const float4*)(pW + kbeg);
    float4 rW1 = *(const float4*)(pW + kbeg + 8);
    float4 rW2 = *(const float4*)(pW + kbeg + 16);
    float4 rW3 = *(const float4*)(pW + kbeg + 24);

    floatx16 acc = {};
    for (int k0 = kbeg; k0 < kend; k0 += 128) {
        __syncthreads();
        *(float4*)&sAh[st0] = rA0; *(float4*)&sAh[st1] = rA1;
        *(float4*)&sAh[st2] = rA2; *(float4*)&sAh[st3] = rA3;
        *(float4*)&sWh[st0] = rW0; *(float4*)&sWh[st1] = rW1;
        *(float4*)&sWh[st2] = rW2; *(float4*)&sWh[st3] = rW3;
        __syncthreads();
        int kn = k0 + 128;
        if (kn < kend) {
            rA0 = *(const float4*)(pA + kn);      rA1 = *(const float4*)(pA + kn + 8);
            rA2 = *(const float4*)(pA + kn + 16); rA3 = *(const float4*)(pA + kn + 24);
            rW0 = *(const float4*)(pW + kn);      rW1 = *(const float4*)(pW + kn + 8);
            rW2 = *(const float4*)(pW + kn + 16); rW3 = *(const float4*)(pW + kn + 24);
        }
#pragma unroll
        for (int kk = 0; kk < 128; kk += 16) {
            int lg = (kk >> 3) + kq;
            half8 ah = *(const half8*)&sAh[arow + ((lg ^ swk) * 8)];
            half8 wh = *(const half8*)&sWh[wrow + ((lg ^ swk) * 8)];
            acc = __builtin_amdgcn_mfma_f32_32x32x16_f16(ah, wh, acc, 0, 0, 0);
        }
    }

    int col = n0 + wn * 32 + rl;
    float bv = (ks == 0) ? bias[col] : 0.f;
    f16* Cp = C + (size_t)ks * Cstride;
#pragma unroll
    for (int rr = 0; rr < 16; ++rr) {
        int row = m0 + wm * 32 + (rr & 3) + 8 * (rr >> 2) + 4 * kq;
        Cp[(size_t)row * ldc + col] = (f16)(acc[rr] + bv);
    }
}

// ---------------------------------------------------------------------------
// V GEMM: pure-f16 weights, BK=64, NREP sweeps n-tiles reusing the A tile.
// ---------------------------------------------------------------------------
__global__ __launch_bounds__(256) void gemm_v(
    const f16* __restrict__ A, int lda,
    const f16* __restrict__ W, int ldw,
    const float* __restrict__ bias, f16* __restrict__ C, int ldc,
    int K, int NT, int MT, int NREP)
{
    __shared__ f16 sAh[64 * 64];
    __shared__ f16 sWh[64 * 64];
    int tid = threadIdx.x, bid = blockIdx.x;
    int nbase = bid % NT;
    int m0 = ((bid / NT) % MT) * 64;
    int lane = tid & 63, wid = tid >> 6;
    int wm = wid >> 1, wn = wid & 1;
    int rl = lane & 31, kq = lane >> 5;
    int sr = tid >> 2;
    int g0 = (tid & 3) * 2;
    int s0 = sr * 64 + ((g0 ^ (sr & 7)) * 8);
    int s1 = sr * 64 + (((g0 + 1) ^ (sr & 7)) * 8);
    int arow = (wm * 32 + rl) * 64;
    int wrow = (wn * 32 + rl) * 64;
    int sw = (rl & 7);

    const f16* pA = A + (size_t)(m0 + sr) * lda + g0 * 8;

    for (int r = 0; r < NREP; ++r) {
        int n0 = (nbase + r * NT) * 64;
        const f16* pW = W + (size_t)(n0 + sr) * ldw + g0 * 8;
        float4 rA0 = *(const float4*)(pA);
        float4 rA1 = *(const float4*)(pA + 8);
        float4 rW0 = *(const float4*)(pW);
        float4 rW1 = *(const float4*)(pW + 8);
        floatx16 acc = {};
        for (int k0 = 0; k0 < K; k0 += 64) {
            __syncthreads();
            *(float4*)&sAh[s0] = rA0; *(float4*)&sAh[s1] = rA1;
            *(float4*)&sWh[s0] = rW0; *(float4*)&sWh[s1] = rW1;
            __syncthreads();
            int kn = k0 + 64;
            if (kn < K) {
                rA0 = *(const float4*)(pA + kn); rA1 = *(const float4*)(pA + kn + 8);
                rW0 = *(const float4*)(pW + kn); rW1 = *(const float4*)(pW + kn + 8);
            }
#pragma unroll
            for (int kk = 0; kk < 64; kk += 16) {
                int lg = (kk >> 3) + kq;
                int off = ((lg ^ sw) * 8);
                half8 ah = *(const half8*)&sAh[arow + off];
                half8 wh = *(const half8*)&sWh[wrow + off];
                acc = __builtin_amdgcn_mfma_f32_32x32x16_f16(ah, wh, acc, 0, 0, 0);
            }
        }
        int col = n0 + wn * 32 + rl;
        float bv = bias[col];
#pragma unroll
        for (int rr = 0; rr < 16; ++rr) {
            int row = m0 + wm * 32 + (rr & 3) + 8 * (rr >> 2) + 4 * kq;
            C[(size_t)row * ldc + col] = (f16)(acc[rr] + bv);
        }
    }
}

// ---------------------------------------------------------------------------
// Encoder step: 512 blocks, one batch per block. Finalize LSTM t-1 from 2
// f16 g-slices (half2 loads), then attention t (f16 t2s, f16 Wc).
// ---------------------------------------------------------------------------
__global__ __launch_bounds__(256) void enc_step_kernel(
    const float* __restrict__ inputs, const f16* __restrict__ t2s,
    const f16* __restrict__ Wcf, const float* __restrict__ bc,
    const float* __restrict__ Wa, const float* __restrict__ ba,
    const f16* __restrict__ g, long long gstride,
    float* __restrict__ hc,
    f16* __restrict__ Ahi, f16* __restrict__ enchi,
    float* __restrict__ hc_dec, f16* __restrict__ hdhi,
    int t) {
    __shared__ float sh_hc[1024];
    __shared__ float t1s[32];
    __shared__ float sred[4];
    int b = blockIdx.x, tid = threadIdx.x;

    if (t > 0) {
        int e = tid * 2;
        const f16* gp = g + (size_t)b * 2048 + e;
        float gi0 = 0.f, gi1 = 0.f, gf0 = 0.f, gf1 = 0.f;
        float gg0 = 0.f, gg1 = 0.f, go0 = 0.f, go1 = 0.f;
#pragma unroll
        for (int s = 0; s < 2; s++) {
            const f16* q = gp + s * gstride;
            half2v a = *(const half2v*)(q);
            half2v f = *(const half2v*)(q + 512);
            half2v gv = *(const half2v*)(q + 1024);
            half2v o = *(const half2v*)(q + 1536);
            gi0 += (float)a[0]; gi1 += (float)a[1];
            gf0 += (float)f[0]; gf1 += (float)f[1];
            gg0 += (float)gv[0]; gg1 += (float)gv[1];
            go0 += (float)o[0]; go1 += (float)o[1];
        }
        float2 cpv = *(const float2*)(hc + b * 1024 + 512 + e);
        float c20 = sigmf(gf0) * cpv.x + sigmf(gi0) * tanh_fast(gg0);
        float c21 = sigmf(gf1) * cpv.y + sigmf(gi1) * tanh_fast(gg1);
        float h20 = sigmf(go0) * tanh_fast(c20);
        float h21 = sigmf(go1) * tanh_fast(c21);
        *(float2*)(hc + b * 1024 + e) = make_float2(h20, h21);
        *(float2*)(hc + b * 1024 + 512 + e) = make_float2(c20, c21);
        sh_hc[e] = h20; sh_hc[e + 1] = h21;
        sh_hc[512 + e] = c20; sh_hc[512 + e + 1] = c21;
        half2v hv; hv[0] = (f16)h20; hv[1] = (f16)h21;
        *(half2v*)(enchi + ((size_t)b * TM1 + (t - 1)) * 512 + e) = hv;
    } else {
        for (int j = tid; j < 1024; j += 256) { sh_hc[j] = 0.f; hc[b * 1024 + j] = 0.f; }
    }
    if (t == TM1) {
        for (int j = tid; j < 1024; j += 256) {
            hc_dec[b * 1024 + j] = 0.f;
            hdhi[b * 1024 + j] = (f16)0.f;
        }
        return;
    }
    __syncthreads();

    if (tid < 248) {
        int s = tid >> 3, l8 = tid & 7;
        const f16* wrow = Wcf + s * 1024;
        float p = 0.f;
        for (int j = l8 * 8; j < 1024; j += 64) {
            half8 w8 = *(const half8*)(wrow + j);
#pragma unroll
            for (int e = 0; e < 8; e++) p += (float)w8[e] * sh_hc[j + e];
        }
        p += __shfl_xor(p, 1); p += __shfl_xor(p, 2); p += __shfl_xor(p, 4);
        if (l8 == 0) t1s[s] = p + bc[s];
    }
    __syncthreads();

    int d = tid;
    float sc = ba[0];
    const f16* t2p = t2s + ((size_t)b * TM1) * DIMD + d;
    for (int s = 0; s < TM1; s++) sc += tanh_fast(t1s[s] + (float)t2p[s * DIMD]) * Wa[s];
    float mx = blockReduceMax256(sc, sred);
    float ex = __expf(sc - mx);
    float sm = blockReduceSum256(ex, sred);
    float w = (ex / sm) * inputs[((size_t)b * TM1 + t) * 257 + 1 + d];
    Ahi[b * 768 + d] = (f16)w;
    for (int j = tid; j < 512; j += 256)
        Ahi[b * 768 + 256 + j] = (f16)sh_hc[j];
}

// ---------------------------------------------------------------------------
// Decoder step: attention (f16 V) + ctx + y_tilde + LSTM pointwise from 2
// f16 gu-slices (half2 loads). Last step fuses final FC.
// ---------------------------------------------------------------------------
__global__ __launch_bounds__(256) void dec_step_kernel(
    const float* __restrict__ inputs, const f16* __restrict__ V,
    const float* __restrict__ W2, const float* __restrict__ b2,
    const f16* __restrict__ enchi,
    const float* __restrict__ fcW, const float* __restrict__ fcb,
    const float* __restrict__ Wih,
    const f16* __restrict__ gu, long long ustride,
    float* __restrict__ hc, f16* __restrict__ hdhi,
    const float* __restrict__ fcfW, const float* __restrict__ fcfb,
    float* __restrict__ out, int t) {
    __shared__ float su[512];
    __shared__ float sw2[512];
    __shared__ float s_att[TM1];
    __shared__ float sred[4];
    int b = blockIdx.x, tid = threadIdx.x;
    const bool last = (t == TM1 - 1);
    {
        int e = tid * 2;
        const f16* q = gu + (size_t)b * 2560 + e;
        half2v a0 = *(const half2v*)(q);
        half2v a1 = *(const half2v*)(q + ustride);
        su[e]     = (float)a0[0] + (float)a1[0];
        su[e + 1] = (float)a0[1] + (float)a1[1];
        sw2[e] = W2[e]; sw2[e + 1] = W2[e + 1];
    }
    __syncthreads();
    if (tid < 248) {
        int tp = tid >> 3, l8 = tid & 7;
        const f16* vrow = V + ((size_t)b * TM1 + tp) * 512;
        float p = 0.f;
        for (int j = l8 * 8; j < 512; j += 64) {
            half8 v8 = *(const half8*)(vrow + j);
#pragma unroll
            for (int e = 0; e < 8; e++)
                p += tanh_fast(su[j + e] + (float)v8[e]) * sw2[j + e];
        }
        p += __shfl_xor(p, 1); p += __shfl_xor(p, 2); p += __shfl_xor(p, 4);
        if (l8 == 0) s_att[tp] = p + b2[0];
    }
    __syncthreads();
    if (tid < 64) {
        float v = (tid < TM1) ? s_att[tid] : -3.4e38f;
        float m = v;
#pragma unroll
        for (int k = 32; k > 0; k >>= 1) m = fmaxf(m, __shfl_xor(m, k));
        float e = (tid < TM1) ? __expf(v - m) : 0.f;
        float s = e;
#pragma unroll
        for (int k = 32; k > 0; k >>= 1) s += __shfl_xor(s, k);
        if (tid < TM1) s_att[tid] = e / s;
    }
    __syncthreads();

    float part = 0.f;
    float pctx = 0.f;
#pragma unroll
    for (int r = 0; r < 2; r++) {
        int e = tid + r * 256;
        float cx = 0.f;
        const f16* eh = enchi + (size_t)b * TM1 * 512 + e;
        for (int tp = 0; tp < TM1; tp++)
            cx += s_att[tp] * (float)eh[tp * 512];
        part += cx * fcW[e];
        if (last) pctx += cx * fcfW[512 + e];
    }
    float y = inputs[((size_t)b * TM1 + t) * 257];
    float ysum = blockReduceSum256(part, sred);
    float y_til = ysum + y * fcW[512] + fcb[0];

    float ph = 0.f;
    {
        int e = tid * 2;
        const f16* q = gu + (size_t)b * 2560 + e;
        float gi0 = 0.f, gi1 = 0.f, gf0 = 0.f, gf1 = 0.f;
        float gg0 = 0.f, gg1 = 0.f, go0 = 0.f, go1 = 0.f;
#pragma unroll
        for (int s = 0; s < 2; s++) {
            const f16* qq = q + s * ustride;
            half2v a = *(const half2v*)(qq + 512);
            half2v f = *(const half2v*)(qq + 1024);
            half2v gv = *(const half2v*)(qq + 1536);
            half2v o = *(const half2v*)(qq + 2048);
            gi0 += (float)a[0]; gi1 += (float)a[1];
            gf0 += (float)f[0]; gf1 += (float)f[1];
            gg0 += (float)gv[0]; gg1 += (float)gv[1];
            go0 += (float)o[0]; go1 += (float)o[1];
        }
        gi0 += y_til * Wih[e];        gi1 += y_til * Wih[e + 1];
        gf0 += y_til * Wih[512 + e];  gf1 += y_til * Wih[512 + e + 1];
        gg0 += y_til * Wih[1024 + e]; gg1 += y_til * Wih[1024 + e + 1];
        go0 += y_til * Wih[1536 + e]; go1 += y_til * Wih[1536 + e + 1];
        float2 cpv = *(const float2*)(hc + b * 1024 + 512 + e);
        float c20 = sigmf(gf0) * cpv.x + sigmf(gi0) * tanh_fast(gg0);
        float c21 = sigmf(gf1) * cpv.y + sigmf(gi1) * tanh_fast(gg1);
        float h20 = sigmf(go0) * tanh_fast(c20);
        float h21 = sigmf(go1) * tanh_fast(c21);
        if (!last) {
            *(float2*)(hc + b * 1024 + e) = make_float2(h20, h21);
            *(float2*)(hc + b * 1024 + 512 + e) = make_float2(c20, c21);
            half2v hv; hv[0] = (f16)h20; hv[1] = (f16)h21;
            half2v cv; cv[0] = (f16)c20; cv[1] = (f16)c21;
            *(half2v*)(hdhi + (size_t)b * 1024 + e) = hv;
            *(half2v*)(hdhi + (size_t)b * 1024 + 512 + e) = cv;
        } else {
            ph += h20 * fcfW[e] + h21 * fcfW[e + 1];
        }
    }
    if (last) {
        float s = blockReduceSum256(ph + pctx, sred);
        if (tid == 0) out[b] = s + fcfb[0];
    }
}

extern "C" void kernel_launch(void* const* d_in, const int* in_sizes, int n_in,
                              void* d_out, int out_size, void* d_ws, size_t ws_size,
                              hipStream_t stream) {
    const float* inputs  = (const float*)d_in[0];
    const float* eWih    = (const float*)d_in[1];
    const float* eWhh    = (const float*)d_in[2];
    const float* ebih    = (const float*)d_in[3];
    const float* ebhh    = (const float*)d_in[4];
    const float* eWc     = (const float*)d_in[5];
    const float* ebc     = (const float*)d_in[6];
    const float* eWd     = (const float*)d_in[7];
    const float* ebd     = (const float*)d_in[8];
    const float* eWa     = (const float*)d_in[9];
    const float* eba     = (const float*)d_in[10];
    const float* dW1     = (const float*)d_in[11];
    const float* db1     = (const float*)d_in[12];
    const float* dW2     = (const float*)d_in[13];
    const float* db2     = (const float*)d_in[14];
    const float* dWih    = (const float*)d_in[15];
    const float* dWhh    = (const float*)d_in[16];
    const float* dbih    = (const float*)d_in[17];
    const float* dbhh    = (const float*)d_in[18];
    const float* fcW     = (const float*)d_in[19];
    const float* fcb     = (const float*)d_in[20];
    const float* fcfW    = (const float*)d_in[21];
    const float* fcfb    = (const float*)d_in[22];
    float* out = (float*)d_out;

    float* scr = (float*)d_ws;
    // ---- union A: t2s f16 (enc) | V f16 (dec) ----
    f16* t2s = (f16*)scr;                       // 4,063,232 h
    f16* Vf  = (f16*)scr;                       // 8,126,464 h
    // ---- union B: g slices (enc) | gu slices (dec), KS=2 ----
    f16* g0e = (f16*)(scr + 4063232);           // 2 x 1,048,576 h
    f16* gu0 = (f16*)(scr + 4063232);           // 2 x 1,310,720 h
    // ---- dedicated ----
    float* hc_enc = scr + 6684672;              //   524,288 f
    f16*   Ahi    = (f16*)(scr + 7208960);      //   393,216 h
    float* hc_dec = scr + 7405568;              //   524,288 f
    f16*   hdhi   = (f16*)(scr + 7929856);      //   524,288 h
    // ---- persistent (pure f16 weights) ----
    f16* fp = (f16*)(scr + 8192000);
    f16* eWf   = fp;             fp += 1572864;
    f16* dWcf  = fp;             fp += 2621440;
    f16* Vwf   = fp;             fp += 262144;
    f16* enchi = fp;             fp += 8126464;
    float* ebcomb = (float*)(((uintptr_t)fp + 15) & ~(uintptr_t)15);
    float* dbias  = ebcomb + 2048;              // 2560 f
    f16* Wcf = (f16*)(dbias + 2560);            // 31,744 h

    hipLaunchKernelGGL(prep_t2s_kernel, dim3(512), dim3(256), 0, stream,
                       inputs, eWih, eWhh, ebih, ebhh, dW1, dWhh, dbih, dbhh,
                       eWd, ebd, eWc, eWf, dWcf, Vwf,
                       ebcomb, dbias, t2s, Wcf);

    const long long gstride = 1048576;   // halves per g slice
    const long long ustride = 1310720;   // halves per gu slice

    // -------- encoder --------
    for (int t = 0; t < TM1; t++) {
        hipLaunchKernelGGL(enc_step_kernel, dim3(BATCH), dim3(256), 0, stream,
                           inputs, t2s, Wcf, ebc, eWa, eba, g0e, gstride, hc_enc,
                           Ahi, enchi, hc_dec, hdhi, t);
        // M=512,N=2048,K=768 split-K2 BK=128: NT=32, MT=8, KS=2 -> 512 blocks
        hipLaunchKernelGGL(gemm1f, dim3(512), dim3(256), 0, stream,
                           Ahi, 768, eWf, 768, ebcomb,
                           g0e, 2048, gstride, 768, 1 << 30, 32, 8, 2);
    }
    hipLaunchKernelGGL(enc_step_kernel, dim3(BATCH), dim3(256), 0, stream,
                       inputs, t2s, Wcf, ebc, eWa, eba, g0e, gstride, hc_enc,
                       Ahi, enchi, hc_dec, hdhi, TM1);

    // -------- V = enc_out @ dec_W1[:,1024:]^T + b1 (f16 out) --------
    hipLaunchKernelGGL(gemm_v, dim3(992), dim3(256), 0, stream,
                       enchi, 512, Vwf, 512, db1,
                       Vf, 512, 512, 4, 248, 2);

    // -------- decoder --------
    for (int t = 0; t < TM1; t++) {
        // M=512,N=2560 split-K2 BK=128: NT=40, MT=8, KS=2 -> 640 blocks
        hipLaunchKernelGGL(gemm1f, dim3(640), dim3(256), 0, stream,
                           hdhi, 1024, dWcf, 1024, dbias,
                           gu0, 2560, ustride, 1024, 512, 40, 8, 2);
        hipLaunchKernelGGL(dec_step_kernel, dim3(BATCH), dim3(256), 0, stream,
                           inputs, Vf, dW2, db2, enchi, fcW, fcb, dWih,
                           gu0, ustride, hc_dec, hdhi, fcfW, fcfb, out, t);
    }
}

// Round 14
// 1440.626 us; speedup vs baseline: 2.9181x; 1.0031x over previous
//
#include <hip/hip_runtime.h>
#include <math.h>

#define BATCH 512
#define TM1   31
#define DIMD  256

typedef _Float16 f16;
typedef _Float16 half2v __attribute__((ext_vector_type(2)));
typedef _Float16 half8 __attribute__((ext_vector_type(8)));
typedef float floatx16 __attribute__((ext_vector_type(16)));

__device__ __forceinline__ float sigmf(float x) { return 1.f / (1.f + __expf(-x)); }

__device__ __forceinline__ float tanh_fast(float x) {
    float ax = fabsf(x);
    float t  = __expf(-2.f * ax);
    float r  = (1.f - t) / (1.f + t);
    return copysignf(r, x);
}

__device__ __forceinline__ float blockReduceSum256(float v, float* sred) {
#pragma unroll
    for (int m = 32; m > 0; m >>= 1) v += __shfl_xor(v, m);
    __syncthreads();
    if ((threadIdx.x & 63) == 0) sred[threadIdx.x >> 6] = v;
    __syncthreads();
    return sred[0] + sred[1] + sred[2] + sred[3];
}

__device__ __forceinline__ float blockReduceMax256(float v, float* sred) {
#pragma unroll
    for (int m = 32; m > 0; m >>= 1) v = fmaxf(v, __shfl_xor(v, m));
    __syncthreads();
    if ((threadIdx.x & 63) == 0) sred[threadIdx.x >> 6] = v;
    __syncthreads();
    return fmaxf(fmaxf(sred[0], sred[1]), fmaxf(sred[2], sred[3]));
}

// ---------------------------------------------------------------------------
// prep + t2s fused. Pure-f16 weight conversion. Dynamic grid-stride (R14:
// launch 2048 blocks — prep was latency-bound at 1.1 TB/s with 512).
// Blocks 0..511 also compute t2s for their batch.
// ---------------------------------------------------------------------------
__global__ __launch_bounds__(256) void prep_t2s_kernel(
    const float* __restrict__ inputs,
    const float* __restrict__ eWih, const float* __restrict__ eWhh,
    const float* __restrict__ ebih, const float* __restrict__ ebhh,
    const float* __restrict__ dW1,  const float* __restrict__ dWhh,
    const float* __restrict__ dbih, const float* __restrict__ dbhh,
    const float* __restrict__ Wd,   const float* __restrict__ bd,
    const float* __restrict__ Wc,
    f16* __restrict__ eWf, f16* __restrict__ dWcf, f16* __restrict__ Vwf,
    float* __restrict__ ebcomb, float* __restrict__ dbias,
    f16* __restrict__ t2s, f16* __restrict__ Wcf)
{
    __shared__ float sX[TM1 * DIMD];
    __shared__ float sWd[TM1 * TM1];
    int b = blockIdx.x, tid = threadIdx.x;
    int idx = b * 256 + tid;
    const int stride = gridDim.x * 256;

    // ---- t2s for batch b (blocks 0..511 only) ----
    if (b < 512) {
        for (int i = tid; i < TM1 * DIMD; i += 256) {
            int tt = i >> 8, d = i & 255;
            sX[i] = inputs[((size_t)b * TM1 + tt) * 257 + 1 + d];
        }
        for (int i = tid; i < TM1 * TM1; i += 256) sWd[i] = Wd[i];
        __syncthreads();
        int d = tid;
        for (int s = 0; s < TM1; s++) {
            float acc = bd[s];
            for (int tt = 0; tt < TM1; tt++) acc += sX[tt * DIMD + d] * sWd[s * TM1 + tt];
            t2s[((size_t)b * TM1 + s) * DIMD + d] = (f16)acc;
        }
    }

    // ---- eW -> f16 ----
    for (int g = idx; g < 2048 * 96; g += stride) {
        int n = g / 96, k0 = (g % 96) * 8;
        const float* src = (k0 < 256) ? (eWih + n * 256 + k0)
                                      : (eWhh + n * 512 + (k0 - 256));
        float4 v0 = *(const float4*)src;
        float4 v1 = *(const float4*)(src + 4);
        f16 h[8] = {(f16)v0.x, (f16)v0.y, (f16)v0.z, (f16)v0.w,
                    (f16)v1.x, (f16)v1.y, (f16)v1.z, (f16)v1.w};
        *(half8*)(eWf + n * 768 + k0) = *(half8*)h;
    }
    // ---- dWc -> f16 ----
    for (int g = idx; g < 2560 * 128; g += stride) {
        int n = g >> 7, k0 = (g & 127) * 8;
        float vv[8] = {};
        if (n < 512) {
            const float* src = dW1 + n * 1536 + k0;
            float4 v0 = *(const float4*)src, v1 = *(const float4*)(src + 4);
            vv[0]=v0.x; vv[1]=v0.y; vv[2]=v0.z; vv[3]=v0.w;
            vv[4]=v1.x; vv[5]=v1.y; vv[6]=v1.z; vv[7]=v1.w;
        } else if (k0 < 512) {
            const float* src = dWhh + (n - 512) * 512 + k0;
            float4 v0 = *(const float4*)src, v1 = *(const float4*)(src + 4);
            vv[0]=v0.x; vv[1]=v0.y; vv[2]=v0.z; vv[3]=v0.w;
            vv[4]=v1.x; vv[5]=v1.y; vv[6]=v1.z; vv[7]=v1.w;
        }
        f16 h[8];
#pragma unroll
        for (int e = 0; e < 8; e++) h[e] = (f16)vv[e];
        *(half8*)(dWcf + n * 1024 + k0) = *(half8*)h;
    }
    // ---- Vw -> f16 ----
    for (int g = idx; g < 512 * 64; g += stride) {
        int n = g >> 6, k0 = (g & 63) * 8;
        const float* src = dW1 + n * 1536 + 1024 + k0;
        float4 v0 = *(const float4*)src, v1 = *(const float4*)(src + 4);
        f16 h[8] = {(f16)v0.x, (f16)v0.y, (f16)v0.z, (f16)v0.w,
                    (f16)v1.x, (f16)v1.y, (f16)v1.z, (f16)v1.w};
        *(half8*)(Vwf + n * 512 + k0) = *(half8*)h;
    }
    // ---- Wc -> f16 ----
    for (int g = idx; g < 3968; g += stride) {
        int k0 = g * 8;
        float4 v0 = *(const float4*)(Wc + k0);
        float4 v1 = *(const float4*)(Wc + k0 + 4);
        f16 h[8] = {(f16)v0.x, (f16)v0.y, (f16)v0.z, (f16)v0.w,
                    (f16)v1.x, (f16)v1.y, (f16)v1.z, (f16)v1.w};
        *(half8*)(Wcf + k0) = *(half8*)h;
    }
    for (int i = idx; i < 2048; i += stride) ebcomb[i] = ebih[i] + ebhh[i];
    for (int i = idx; i < 2560; i += stride)
        dbias[i] = (i < 512) ? 0.f : (dbih[i - 512] + dbhh[i - 512]);
}

// ---------------------------------------------------------------------------
// Step GEMM: pure-f16, split-K2, f16 out, BK=128 (R12/R13-validated).
// ---------------------------------------------------------------------------
__global__ __launch_bounds__(256) void gemm1f(
    const f16* __restrict__ A, int lda,
    const f16* __restrict__ W, int ldw,
    const float* __restrict__ bias, f16* __restrict__ C, int ldc,
    long long Cstride, int K, int nsplit, int NT, int MT, int KS)
{
    __shared__ f16 sAh[64 * 128];
    __shared__ f16 sWh[64 * 128];
    int tid = threadIdx.x, bid = blockIdx.x;
    int nbase = bid % NT;
    int m0 = ((bid / NT) % MT) * 64;
    int ks = bid / (NT * MT);
    int lane = tid & 63, wid = tid >> 6;
    int wm = wid >> 1, wn = wid & 1;
    int rl = lane & 31, kq = lane >> 5;

    int sr = tid >> 2;
    int gb = (tid & 3) * 4;
    int st0 = sr * 128 + (((gb + 0) ^ (sr & 15)) * 8);
    int st1 = sr * 128 + (((gb + 1) ^ (sr & 15)) * 8);
    int st2 = sr * 128 + (((gb + 2) ^ (sr & 15)) * 8);
    int st3 = sr * 128 + (((gb + 3) ^ (sr & 15)) * 8);
    int arow = (wm * 32 + rl) * 128;
    int wrow = (wn * 32 + rl) * 128;
    int swk = rl & 15;

    int n0 = nbase * 64;
    int Kfull = (n0 >= nsplit) ? 512 : K;
    int ksz = Kfull / KS;
    int kbeg = ks * ksz, kend = kbeg + ksz;

    const f16* pA = A + (size_t)(m0 + sr) * lda + gb * 8;
    const f16* pW = W + (size_t)(n0 + sr) * ldw + gb * 8;

    float4 rA0 = *(const float4*)(pA + kbeg);
    float4 rA1 = *(const float4*)(pA + kbeg + 8);
    float4 rA2 = *(const float4*)(pA + kbeg + 16);
    float4 rA3 = *(const float4*)(pA + kbeg + 24);
    float4 rW0 = *(const float4*)(pW + kbeg);
    float4 rW1 = *(const float4*)(pW + kbeg + 8);
    float4 rW2 = *(const float4*)(pW + kbeg + 16);
    float4 rW3 = *(const float4*)(pW + kbeg + 24);

    floatx16 acc = {};
    for (int k0 = kbeg; k0 < kend; k0 += 128) {
        __syncthreads();
        *(float4*)&sAh[st0] = rA0; *(float4*)&sAh[st1] = rA1;
        *(float4*)&sAh[st2] = rA2; *(float4*)&sAh[st3] = rA3;
        *(float4*)&sWh[st0] = rW0; *(float4*)&sWh[st1] = rW1;
        *(float4*)&sWh[st2] = rW2; *(float4*)&sWh[st3] = rW3;
        __syncthreads();
        int kn = k0 + 128;
        if (kn < kend) {
            rA0 = *(const float4*)(pA + kn);      rA1 = *(const float4*)(pA + kn + 8);
            rA2 = *(const float4*)(pA + kn + 16); rA3 = *(const float4*)(pA + kn + 24);
            rW0 = *(const float4*)(pW + kn);      rW1 = *(const float4*)(pW + kn + 8);
            rW2 = *(const float4*)(pW + kn + 16); rW3 = *(const float4*)(pW + kn + 24);
        }
#pragma unroll
        for (int kk = 0; kk < 128; kk += 16) {
            int lg = (kk >> 3) + kq;
            half8 ah = *(const half8*)&sAh[arow + ((lg ^ swk) * 8)];
            half8 wh = *(const half8*)&sWh[wrow + ((lg ^ swk) * 8)];
            acc = __builtin_amdgcn_mfma_f32_32x32x16_f16(ah, wh, acc, 0, 0, 0);
        }
    }

    int col = n0 + wn * 32 + rl;
    float bv = (ks == 0) ? bias[col] : 0.f;
    f16* Cp = C + (size_t)ks * Cstride;
#pragma unroll
    for (int rr = 0; rr < 16; ++rr) {
        int row = m0 + wm * 32 + (rr & 3) + 8 * (rr >> 2) + 4 * kq;
        Cp[(size_t)row * ldc + col] = (f16)(acc[rr] + bv);
    }
}

// ---------------------------------------------------------------------------
// V GEMM: pure-f16, BK=64, NREP sweeps n-tiles reusing the A tile.
// ---------------------------------------------------------------------------
__global__ __launch_bounds__(256) void gemm_v(
    const f16* __restrict__ A, int lda,
    const f16* __restrict__ W, int ldw,
    const float* __restrict__ bias, f16* __restrict__ C, int ldc,
    int K, int NT, int MT, int NREP)
{
    __shared__ f16 sAh[64 * 64];
    __shared__ f16 sWh[64 * 64];
    int tid = threadIdx.x, bid = blockIdx.x;
    int nbase = bid % NT;
    int m0 = ((bid / NT) % MT) * 64;
    int lane = tid & 63, wid = tid >> 6;
    int wm = wid >> 1, wn = wid & 1;
    int rl = lane & 31, kq = lane >> 5;
    int sr = tid >> 2;
    int g0 = (tid & 3) * 2;
    int s0 = sr * 64 + ((g0 ^ (sr & 7)) * 8);
    int s1 = sr * 64 + (((g0 + 1) ^ (sr & 7)) * 8);
    int arow = (wm * 32 + rl) * 64;
    int wrow = (wn * 32 + rl) * 64;
    int sw = (rl & 7);

    const f16* pA = A + (size_t)(m0 + sr) * lda + g0 * 8;

    for (int r = 0; r < NREP; ++r) {
        int n0 = (nbase + r * NT) * 64;
        const f16* pW = W + (size_t)(n0 + sr) * ldw + g0 * 8;
        float4 rA0 = *(const float4*)(pA);
        float4 rA1 = *(const float4*)(pA + 8);
        float4 rW0 = *(const float4*)(pW);
        float4 rW1 = *(const float4*)(pW + 8);
        floatx16 acc = {};
        for (int k0 = 0; k0 < K; k0 += 64) {
            __syncthreads();
            *(float4*)&sAh[s0] = rA0; *(float4*)&sAh[s1] = rA1;
            *(float4*)&sWh[s0] = rW0; *(float4*)&sWh[s1] = rW1;
            __syncthreads();
            int kn = k0 + 64;
            if (kn < K) {
                rA0 = *(const float4*)(pA + kn); rA1 = *(const float4*)(pA + kn + 8);
                rW0 = *(const float4*)(pW + kn); rW1 = *(const float4*)(pW + kn + 8);
            }
#pragma unroll
            for (int kk = 0; kk < 64; kk += 16) {
                int lg = (kk >> 3) + kq;
                int off = ((lg ^ sw) * 8);
                half8 ah = *(const half8*)&sAh[arow + off];
                half8 wh = *(const half8*)&sWh[wrow + off];
                acc = __builtin_amdgcn_mfma_f32_32x32x16_f16(ah, wh, acc, 0, 0, 0);
            }
        }
        int col = n0 + wn * 32 + rl;
        float bv = bias[col];
#pragma unroll
        for (int rr = 0; rr < 16; ++rr) {
            int row = m0 + wm * 32 + (rr & 3) + 8 * (rr >> 2) + 4 * kq;
            C[(size_t)row * ldc + col] = (f16)(acc[rr] + bv);
        }
    }
}

// ---------------------------------------------------------------------------
// Encoder step: finalize LSTM t-1 (only c-half of hc is live in global —
// h is dead there, R14), then attention t.
// ---------------------------------------------------------------------------
__global__ __launch_bounds__(256) void enc_step_kernel(
    const float* __restrict__ inputs, const f16* __restrict__ t2s,
    const f16* __restrict__ Wcf, const float* __restrict__ bc,
    const float* __restrict__ Wa, const float* __restrict__ ba,
    const f16* __restrict__ g, long long gstride,
    float* __restrict__ hc,
    f16* __restrict__ Ahi, f16* __restrict__ enchi,
    float* __restrict__ hc_dec, f16* __restrict__ hdhi,
    int t) {
    __shared__ float sh_hc[1024];
    __shared__ float t1s[32];
    __shared__ float sred[4];
    int b = blockIdx.x, tid = threadIdx.x;

    if (t > 0) {
        int e = tid * 2;
        const f16* gp = g + (size_t)b * 2048 + e;
        float gi0 = 0.f, gi1 = 0.f, gf0 = 0.f, gf1 = 0.f;
        float gg0 = 0.f, gg1 = 0.f, go0 = 0.f, go1 = 0.f;
#pragma unroll
        for (int s = 0; s < 2; s++) {
            const f16* q = gp + s * gstride;
            half2v a = *(const half2v*)(q);
            half2v f = *(const half2v*)(q + 512);
            half2v gv = *(const half2v*)(q + 1024);
            half2v o = *(const half2v*)(q + 1536);
            gi0 += (float)a[0]; gi1 += (float)a[1];
            gf0 += (float)f[0]; gf1 += (float)f[1];
            gg0 += (float)gv[0]; gg1 += (float)gv[1];
            go0 += (float)o[0]; go1 += (float)o[1];
        }
        float2 cpv = *(const float2*)(hc + b * 1024 + 512 + e);
        float c20 = sigmf(gf0) * cpv.x + sigmf(gi0) * tanh_fast(gg0);
        float c21 = sigmf(gf1) * cpv.y + sigmf(gi1) * tanh_fast(gg1);
        float h20 = sigmf(go0) * tanh_fast(c20);
        float h21 = sigmf(go1) * tanh_fast(c21);
        // h-half of hc is dead (finalize reads only c) — store c only.
        *(float2*)(hc + b * 1024 + 512 + e) = make_float2(c20, c21);
        sh_hc[e] = h20; sh_hc[e + 1] = h21;
        sh_hc[512 + e] = c20; sh_hc[512 + e + 1] = c21;
        half2v hv; hv[0] = (f16)h20; hv[1] = (f16)h21;
        *(half2v*)(enchi + ((size_t)b * TM1 + (t - 1)) * 512 + e) = hv;
    } else {
        for (int j = tid; j < 1024; j += 256) { sh_hc[j] = 0.f; }
        for (int j = tid; j < 512; j += 256) hc[b * 1024 + 512 + j] = 0.f;
    }
    if (t == TM1) {
        for (int j = tid; j < 512; j += 256) hc_dec[b * 1024 + 512 + j] = 0.f;
        for (int j = tid; j < 1024; j += 256) hdhi[b * 1024 + j] = (f16)0.f;
        return;
    }
    __syncthreads();

    if (tid < 248) {
        int s = tid >> 3, l8 = tid & 7;
        const f16* wrow = Wcf + s * 1024;
        float p = 0.f;
        for (int j = l8 * 8; j < 1024; j += 64) {
            half8 w8 = *(const half8*)(wrow + j);
#pragma unroll
            for (int e = 0; e < 8; e++) p += (float)w8[e] * sh_hc[j + e];
        }
        p += __shfl_xor(p, 1); p += __shfl_xor(p, 2); p += __shfl_xor(p, 4);
        if (l8 == 0) t1s[s] = p + bc[s];
    }
    __syncthreads();

    int d = tid;
    float sc = ba[0];
    const f16* t2p = t2s + ((size_t)b * TM1) * DIMD + d;
    for (int s = 0; s < TM1; s++) sc += tanh_fast(t1s[s] + (float)t2p[s * DIMD]) * Wa[s];
    float mx = blockReduceMax256(sc, sred);
    float ex = __expf(sc - mx);
    float sm = blockReduceSum256(ex, sred);
    float w = (ex / sm) * inputs[((size_t)b * TM1 + t) * 257 + 1 + d];
    Ahi[b * 768 + d] = (f16)w;
    {
        int j = tid * 2;
        half2v hv; hv[0] = (f16)sh_hc[j]; hv[1] = (f16)sh_hc[j + 1];
        *(half2v*)(Ahi + b * 768 + 256 + j) = hv;
    }
}

// ---------------------------------------------------------------------------
// Decoder step: attention (f16 V) + ctx (half2, R14) + y_tilde + LSTM
// pointwise from 2 f16 gu-slices. hc h-half dead — store c only.
// Last step fuses final FC.
// ---------------------------------------------------------------------------
__global__ __launch_bounds__(256) void dec_step_kernel(
    const float* __restrict__ inputs, const f16* __restrict__ V,
    const float* __restrict__ W2, const float* __restrict__ b2,
    const f16* __restrict__ enchi,
    const float* __restrict__ fcW, const float* __restrict__ fcb,
    const float* __restrict__ Wih,
    const f16* __restrict__ gu, long long ustride,
    float* __restrict__ hc, f16* __restrict__ hdhi,
    const float* __restrict__ fcfW, const float* __restrict__ fcfb,
    float* __restrict__ out, int t) {
    __shared__ float su[512];
    __shared__ float sw2[512];
    __shared__ float s_att[TM1];
    __shared__ float sred[4];
    int b = blockIdx.x, tid = threadIdx.x;
    const bool last = (t == TM1 - 1);
    {
        int e = tid * 2;
        const f16* q = gu + (size_t)b * 2560 + e;
        half2v a0 = *(const half2v*)(q);
        half2v a1 = *(const half2v*)(q + ustride);
        su[e]     = (float)a0[0] + (float)a1[0];
        su[e + 1] = (float)a0[1] + (float)a1[1];
        sw2[e] = W2[e]; sw2[e + 1] = W2[e + 1];
    }
    __syncthreads();
    if (tid < 248) {
        int tp = tid >> 3, l8 = tid & 7;
        const f16* vrow = V + ((size_t)b * TM1 + tp) * 512;
        float p = 0.f;
        for (int j = l8 * 8; j < 512; j += 64) {
            half8 v8 = *(const half8*)(vrow + j);
#pragma unroll
            for (int e = 0; e < 8; e++)
                p += tanh_fast(su[j + e] + (float)v8[e]) * sw2[j + e];
        }
        p += __shfl_xor(p, 1); p += __shfl_xor(p, 2); p += __shfl_xor(p, 4);
        if (l8 == 0) s_att[tp] = p + b2[0];
    }
    __syncthreads();
    if (tid < 64) {
        float v = (tid < TM1) ? s_att[tid] : -3.4e38f;
        float m = v;
#pragma unroll
        for (int k = 32; k > 0; k >>= 1) m = fmaxf(m, __shfl_xor(m, k));
        float e = (tid < TM1) ? __expf(v - m) : 0.f;
        float s = e;
#pragma unroll
        for (int k = 32; k > 0; k >>= 1) s += __shfl_xor(s, k);
        if (tid < TM1) s_att[tid] = e / s;
    }
    __syncthreads();

    // ctx: one half2 column pair per thread (e = 2*tid, 2*tid+1)
    float part, pctx = 0.f;
    {
        int e = tid * 2;
        float cx0 = 0.f, cx1 = 0.f;
        const f16* eh = enchi + (size_t)b * TM1 * 512 + e;
        for (int tp = 0; tp < TM1; tp++) {
            half2v v2 = *(const half2v*)(eh + tp * 512);
            cx0 += s_att[tp] * (float)v2[0];
            cx1 += s_att[tp] * (float)v2[1];
        }
        float2 fw = *(const float2*)(fcW + e);
        part = cx0 * fw.x + cx1 * fw.y;
        if (last) {
            float2 fw2 = *(const float2*)(fcfW + 512 + e);
            pctx = cx0 * fw2.x + cx1 * fw2.y;
        }
    }
    float y = inputs[((size_t)b * TM1 + t) * 257];
    float ysum = blockReduceSum256(part, sred);
    float y_til = ysum + y * fcW[512] + fcb[0];

    float ph = 0.f;
    {
        int e = tid * 2;
        const f16* q = gu + (size_t)b * 2560 + e;
        float gi0 = 0.f, gi1 = 0.f, gf0 = 0.f, gf1 = 0.f;
        float gg0 = 0.f, gg1 = 0.f, go0 = 0.f, go1 = 0.f;
#pragma unroll
        for (int s = 0; s < 2; s++) {
            const f16* qq = q + s * ustride;
            half2v a = *(const half2v*)(qq + 512);
            half2v f = *(const half2v*)(qq + 1024);
            half2v gv = *(const half2v*)(qq + 1536);
            half2v o = *(const half2v*)(qq + 2048);
            gi0 += (float)a[0]; gi1 += (float)a[1];
            gf0 += (float)f[0]; gf1 += (float)f[1];
            gg0 += (float)gv[0]; gg1 += (float)gv[1];
            go0 += (float)o[0]; go1 += (float)o[1];
        }
        gi0 += y_til * Wih[e];        gi1 += y_til * Wih[e + 1];
        gf0 += y_til * Wih[512 + e];  gf1 += y_til * Wih[512 + e + 1];
        gg0 += y_til * Wih[1024 + e]; gg1 += y_til * Wih[1024 + e + 1];
        go0 += y_til * Wih[1536 + e]; go1 += y_til * Wih[1536 + e + 1];
        float2 cpv = *(const float2*)(hc + b * 1024 + 512 + e);
        float c20 = sigmf(gf0) * cpv.x + sigmf(gi0) * tanh_fast(gg0);
        float c21 = sigmf(gf1) * cpv.y + sigmf(gi1) * tanh_fast(gg1);
        float h20 = sigmf(go0) * tanh_fast(c20);
        float h21 = sigmf(go1) * tanh_fast(c21);
        if (!last) {
            // h-half of hc is dead — store c only.
            *(float2*)(hc + b * 1024 + 512 + e) = make_float2(c20, c21);
            half2v hv; hv[0] = (f16)h20; hv[1] = (f16)h21;
            half2v cv; cv[0] = (f16)c20; cv[1] = (f16)c21;
            *(half2v*)(hdhi + (size_t)b * 1024 + e) = hv;
            *(half2v*)(hdhi + (size_t)b * 1024 + 512 + e) = cv;
        } else {
            ph += h20 * fcfW[e] + h21 * fcfW[e + 1];
        }
    }
    if (last) {
        float s = blockReduceSum256(ph + pctx, sred);
        if (tid == 0) out[b] = s + fcfb[0];
    }
}

extern "C" void kernel_launch(void* const* d_in, const int* in_sizes, int n_in,
                              void* d_out, int out_size, void* d_ws, size_t ws_size,
                              hipStream_t stream) {
    const float* inputs  = (const float*)d_in[0];
    const float* eWih    = (const float*)d_in[1];
    const float* eWhh    = (const float*)d_in[2];
    const float* ebih    = (const float*)d_in[3];
    const float* ebhh    = (const float*)d_in[4];
    const float* eWc     = (const float*)d_in[5];
    const float* ebc     = (const float*)d_in[6];
    const float* eWd     = (const float*)d_in[7];
    const float* ebd     = (const float*)d_in[8];
    const float* eWa     = (const float*)d_in[9];
    const float* eba     = (const float*)d_in[10];
    const float* dW1     = (const float*)d_in[11];
    const float* db1     = (const float*)d_in[12];
    const float* dW2     = (const float*)d_in[13];
    const float* db2     = (const float*)d_in[14];
    const float* dWih    = (const float*)d_in[15];
    const float* dWhh    = (const float*)d_in[16];
    const float* dbih    = (const float*)d_in[17];
    const float* dbhh    = (const float*)d_in[18];
    const float* fcW     = (const float*)d_in[19];
    const float* fcb     = (const float*)d_in[20];
    const float* fcfW    = (const float*)d_in[21];
    const float* fcfb    = (const float*)d_in[22];
    float* out = (float*)d_out;

    float* scr = (float*)d_ws;
    // ---- union A: t2s f16 (enc) | V f16 (dec) ----
    f16* t2s = (f16*)scr;                       // 4,063,232 h
    f16* Vf  = (f16*)scr;                       // 8,126,464 h
    // ---- union B: g slices (enc) | gu slices (dec), KS=2 ----
    f16* g0e = (f16*)(scr + 4063232);           // 2 x 1,048,576 h
    f16* gu0 = (f16*)(scr + 4063232);           // 2 x 1,310,720 h
    // ---- dedicated ----
    float* hc_enc = scr + 6684672;              //   524,288 f
    f16*   Ahi    = (f16*)(scr + 7208960);      //   393,216 h
    float* hc_dec = scr + 7405568;              //   524,288 f
    f16*   hdhi   = (f16*)(scr + 7929856);      //   524,288 h
    // ---- persistent (pure f16 weights) ----
    f16* fp = (f16*)(scr + 8192000);
    f16* eWf   = fp;             fp += 1572864;
    f16* dWcf  = fp;             fp += 2621440;
    f16* Vwf   = fp;             fp += 262144;
    f16* enchi = fp;             fp += 8126464;
    float* ebcomb = (float*)(((uintptr_t)fp + 15) & ~(uintptr_t)15);
    float* dbias  = ebcomb + 2048;              // 2560 f
    f16* Wcf = (f16*)(dbias + 2560);            // 31,744 h

    hipLaunchKernelGGL(prep_t2s_kernel, dim3(2048), dim3(256), 0, stream,
                       inputs, eWih, eWhh, ebih, ebhh, dW1, dWhh, dbih, dbhh,
                       eWd, ebd, eWc, eWf, dWcf, Vwf,
                       ebcomb, dbias, t2s, Wcf);

    const long long gstride = 1048576;   // halves per g slice
    const long long ustride = 1310720;   // halves per gu slice

    // -------- encoder --------
    for (int t = 0; t < TM1; t++) {
        hipLaunchKernelGGL(enc_step_kernel, dim3(BATCH), dim3(256), 0, stream,
                           inputs, t2s, Wcf, ebc, eWa, eba, g0e, gstride, hc_enc,
                           Ahi, enchi, hc_dec, hdhi, t);
        hipLaunchKernelGGL(gemm1f, dim3(512), dim3(256), 0, stream,
                           Ahi, 768, eWf, 768, ebcomb,
                           g0e, 2048, gstride, 768, 1 << 30, 32, 8, 2);
    }
    hipLaunchKernelGGL(enc_step_kernel, dim3(BATCH), dim3(256), 0, stream,
                       inputs, t2s, Wcf, ebc, eWa, eba, g0e, gstride, hc_enc,
                       Ahi, enchi, hc_dec, hdhi, TM1);

    // -------- V = enc_out @ dec_W1[:,1024:]^T + b1 (f16 out) --------
    hipLaunchKernelGGL(gemm_v, dim3(992), dim3(256), 0, stream,
                       enchi, 512, Vwf, 512, db1,
                       Vf, 512, 512, 4, 248, 2);

    // -------- decoder --------
    for (int t = 0; t < TM1; t++) {
        hipLaunchKernelGGL(gemm1f, dim3(640), dim3(256), 0, stream,
                           hdhi, 1024, dWcf, 1024, dbias,
                           gu0, 2560, ustride, 1024, 512, 40, 8, 2);
        hipLaunchKernelGGL(dec_step_kernel, dim3(BATCH), dim3(256), 0, stream,
                           inputs, Vf, dW2, db2, enchi, fcW, fcb, dWih,
                           gu0, ustride, hc_dec, hdhi, fcfW, fcfb, out, t);
    }
}